// Round 1
// baseline (1609.467 us; speedup 1.0000x reference)
//
#include <hip/hip_runtime.h>
#include <math.h>

// Problem constants (fixed by reference)
#define Bsz   4
#define Tsz   2048
#define Dsz   1024
#define Hsz   16
#define Lsz   64
#define BHsz  64          // B*H
#define CH    64          // chunk length
#define NCH   32          // T / CH
#define QKVLD 3072        // qkv row stride (3*D)
#define SCL   0.125f      // 1/sqrt(64)

static __device__ __forceinline__ float wave_max64(float v) {
#pragma unroll
  for (int off = 1; off < 64; off <<= 1) v = fmaxf(v, __shfl_xor(v, off));
  return v;
}
static __device__ __forceinline__ float wave_sum64(float v) {
#pragma unroll
  for (int off = 1; off < 64; off <<= 1) v += __shfl_xor(v, off);
  return v;
}

// ---------------------------------------------------------------------------
// GEMM NT: C[m][n] = sum_k A[m][k] * B[n][k]   (both K-contiguous)
// 64x64 tile, BK=16, 256 threads, 4x4 microtile.
// ---------------------------------------------------------------------------
__launch_bounds__(256)
__global__ void gemm_nt64(const float* __restrict__ A, const float* __restrict__ Bm,
                          float* __restrict__ C, int M, int N, int K) {
  __shared__ __align__(16) float As[16][68];
  __shared__ __align__(16) float Bs[16][68];
  const int tid  = threadIdx.x;
  const int m0   = blockIdx.y * 64;
  const int n0   = blockIdx.x * 64;
  const int lrow = tid >> 2;          // 0..63
  const int lseg = (tid & 3) * 4;     // 0,4,8,12
  const int ty   = tid >> 4;          // 0..15
  const int tx   = tid & 15;          // 0..15
  float acc[4][4];
#pragma unroll
  for (int i = 0; i < 4; i++)
#pragma unroll
    for (int j = 0; j < 4; j++) acc[i][j] = 0.f;

  for (int k0 = 0; k0 < K; k0 += 16) {
    float4 av = *(const float4*)(A + (size_t)(m0 + lrow) * K + k0 + lseg);
    float4 bv = *(const float4*)(Bm + (size_t)(n0 + lrow) * K + k0 + lseg);
    __syncthreads();
    As[lseg + 0][lrow] = av.x; As[lseg + 1][lrow] = av.y;
    As[lseg + 2][lrow] = av.z; As[lseg + 3][lrow] = av.w;
    Bs[lseg + 0][lrow] = bv.x; Bs[lseg + 1][lrow] = bv.y;
    Bs[lseg + 2][lrow] = bv.z; Bs[lseg + 3][lrow] = bv.w;
    __syncthreads();
#pragma unroll
    for (int kk = 0; kk < 16; kk++) {
      float4 a = *(const float4*)&As[kk][ty * 4];
      float4 b = *(const float4*)&Bs[kk][tx * 4];
      acc[0][0] += a.x * b.x; acc[0][1] += a.x * b.y; acc[0][2] += a.x * b.z; acc[0][3] += a.x * b.w;
      acc[1][0] += a.y * b.x; acc[1][1] += a.y * b.y; acc[1][2] += a.y * b.z; acc[1][3] += a.y * b.w;
      acc[2][0] += a.z * b.x; acc[2][1] += a.z * b.y; acc[2][2] += a.z * b.z; acc[2][3] += a.z * b.w;
      acc[3][0] += a.w * b.x; acc[3][1] += a.w * b.y; acc[3][2] += a.w * b.z; acc[3][3] += a.w * b.w;
    }
  }
#pragma unroll
  for (int i = 0; i < 4; i++) {
    float4 o = make_float4(acc[i][0], acc[i][1], acc[i][2], acc[i][3]);
    *(float4*)(C + (size_t)(m0 + ty * 4 + i) * N + n0 + tx * 4) = o;
  }
}

// ---------------------------------------------------------------------------
// GEMM NN: C[m][n] = sum_k A[m][k] * B[k][n]   (A K-contig, B N-contig)
// ---------------------------------------------------------------------------
__launch_bounds__(256)
__global__ void gemm_nn64(const float* __restrict__ A, const float* __restrict__ Bm,
                          float* __restrict__ C, int M, int N, int K) {
  __shared__ __align__(16) float As[16][68];
  __shared__ __align__(16) float Bs[16][68];
  const int tid  = threadIdx.x;
  const int m0   = blockIdx.y * 64;
  const int n0   = blockIdx.x * 64;
  const int lrow = tid >> 2;          // 0..63 (A tile row)
  const int lseg = (tid & 3) * 4;
  const int brow = tid >> 4;          // 0..15 (B tile k-row)
  const int bseg = (tid & 15) * 4;    // 0..60 (B tile n-seg)
  const int ty   = tid >> 4;
  const int tx   = tid & 15;
  float acc[4][4];
#pragma unroll
  for (int i = 0; i < 4; i++)
#pragma unroll
    for (int j = 0; j < 4; j++) acc[i][j] = 0.f;

  for (int k0 = 0; k0 < K; k0 += 16) {
    float4 av = *(const float4*)(A + (size_t)(m0 + lrow) * K + k0 + lseg);
    float4 bv = *(const float4*)(Bm + (size_t)(k0 + brow) * N + n0 + bseg);
    __syncthreads();
    As[lseg + 0][lrow] = av.x; As[lseg + 1][lrow] = av.y;
    As[lseg + 2][lrow] = av.z; As[lseg + 3][lrow] = av.w;
    *(float4*)&Bs[brow][bseg] = bv;
    __syncthreads();
#pragma unroll
    for (int kk = 0; kk < 16; kk++) {
      float4 a = *(const float4*)&As[kk][ty * 4];
      float4 b = *(const float4*)&Bs[kk][tx * 4];
      acc[0][0] += a.x * b.x; acc[0][1] += a.x * b.y; acc[0][2] += a.x * b.z; acc[0][3] += a.x * b.w;
      acc[1][0] += a.y * b.x; acc[1][1] += a.y * b.y; acc[1][2] += a.y * b.z; acc[1][3] += a.y * b.w;
      acc[2][0] += a.z * b.x; acc[2][1] += a.z * b.y; acc[2][2] += a.z * b.z; acc[2][3] += a.z * b.w;
      acc[3][0] += a.w * b.x; acc[3][1] += a.w * b.y; acc[3][2] += a.w * b.z; acc[3][3] += a.w * b.w;
    }
  }
#pragma unroll
  for (int i = 0; i < 4; i++) {
    float4 o = make_float4(acc[i][0], acc[i][1], acc[i][2], acc[i][3]);
    *(float4*)(C + (size_t)(m0 + ty * 4 + i) * N + n0 + tx * 4) = o;
  }
}

// ---------------------------------------------------------------------------
// Per-chunk KV outer-product sums + per-chunk kexp sums.
// grid (BH, NCH), 64 threads. lane = column m; S[l] = state column.
// ---------------------------------------------------------------------------
__launch_bounds__(64)
__global__ void chunk_kv(const float* __restrict__ qkv, float* __restrict__ KV,
                         float* __restrict__ Ksum) {
  const int bh = blockIdx.x, c = blockIdx.y;
  const int b = bh >> 4, h = bh & 15;
  const int lane = threadIdx.x;
  __shared__ __align__(16) float kex[64];
  float S[64];
#pragma unroll
  for (int i = 0; i < 64; i++) S[i] = 0.f;
  float ksum = 0.f;
  const size_t base = ((size_t)(b * Tsz + c * CH)) * QKVLD + h * 64;
  for (int t = 0; t < CH; t++) {
    const float* row = qkv + base + (size_t)t * QKVLD;
    float ke = expf(row[1024 + lane] * SCL) + 1e-6f;  // lane as l
    float v  = row[2048 + lane];                       // lane as m
    ksum += ke;
    __syncthreads();
    kex[lane] = ke;
    __syncthreads();
    const float4* k4 = (const float4*)kex;
#pragma unroll
    for (int l4 = 0; l4 < 16; l4++) {
      float4 kk = k4[l4];
      S[l4 * 4 + 0] += kk.x * v;
      S[l4 * 4 + 1] += kk.y * v;
      S[l4 * 4 + 2] += kk.z * v;
      S[l4 * 4 + 3] += kk.w * v;
    }
  }
  float* KVp = KV + ((size_t)(bh * NCH + c)) * 4096;
#pragma unroll
  for (int l = 0; l < 64; l++) KVp[l * 64 + lane] = S[l];
  Ksum[(bh * NCH + c) * 64 + lane] = ksum;
}

// ---------------------------------------------------------------------------
// In-place exclusive prefix over chunks of KV state and Ksum. grid = BH.
// ---------------------------------------------------------------------------
__launch_bounds__(256)
__global__ void prefix_kern(float* __restrict__ KV, float* __restrict__ Ksum) {
  const int bh = blockIdx.x;
  const int tid = threadIdx.x;
#pragma unroll
  for (int i = 0; i < 16; i++) {
    const int e = tid + i * 256;
    float acc = 0.f;
    float* p = KV + (size_t)bh * NCH * 4096 + e;
    for (int c = 0; c < NCH; c++) {
      float t = p[(size_t)c * 4096];
      p[(size_t)c * 4096] = acc;
      acc += t;
    }
  }
  if (tid < 64) {
    float acc = 0.f;
    float* p = Ksum + bh * NCH * 64 + tid;
    for (int c = 0; c < NCH; c++) {
      float t = p[c * 64];
      p[c * 64] = acc;
      acc += t;
    }
  }
}

// ---------------------------------------------------------------------------
// Per-chunk output: y_t = qs_t . (Sprefix + intra-chunk causal KV).
// grid (BH, NCH), 256 threads. LDS: q/qs, kexp, v, knorm->A, Sprefix (80 KB).
// ---------------------------------------------------------------------------
__launch_bounds__(256)
__global__ void chunk_y(const float* __restrict__ qkv, const float* __restrict__ KV,
                        const float* __restrict__ Ksum, float* __restrict__ Y) {
  const int bh = blockIdx.x, c = blockIdx.y;
  const int b = bh >> 4, h = bh & 15;
  const int tid = threadIdx.x;
  __shared__ __align__(16) float qs[64][64];  // raw q, then qs
  __shared__ __align__(16) float kx[64][64];  // kexp
  __shared__ __align__(16) float vb[64][64];  // v
  __shared__ __align__(16) float kn[64][64];  // knorm, then A (scores)
  __shared__ __align__(16) float Sp[64][64];  // state prefix

  const size_t base = ((size_t)(b * Tsz + c * CH)) * QKVLD + h * 64;
  const float* KVp = KV + ((size_t)(bh * NCH + c)) * 4096;
  {
    const int r0 = tid >> 4;            // 0..15
    const int seg4 = (tid & 15) * 4;    // 0..60
#pragma unroll
    for (int pass = 0; pass < 4; ++pass) {
      const int t = pass * 16 + r0;
      const float* row = qkv + base + (size_t)t * QKVLD;
      float4 qv = *(const float4*)(row + seg4);
      *(float4*)&qs[t][seg4] = qv;
      float4 kv = *(const float4*)(row + 1024 + seg4);
      kx[t][seg4 + 0] = expf(kv.x * SCL) + 1e-6f;
      kx[t][seg4 + 1] = expf(kv.y * SCL) + 1e-6f;
      kx[t][seg4 + 2] = expf(kv.z * SCL) + 1e-6f;
      kx[t][seg4 + 3] = expf(kv.w * SCL) + 1e-6f;
      float4 vv = *(const float4*)(row + 2048 + seg4);
      *(float4*)&vb[t][seg4] = vv;
      float4 sp = *(const float4*)(KVp + t * 64 + seg4);
      *(float4*)&Sp[t][seg4] = sp;
    }
  }
  __syncthreads();

  // knorm: exclusive chunk prefix + inclusive intra-chunk cumsum (lane = l)
  if (tid < 64) {
    float acc = Ksum[(bh * NCH + c) * 64 + tid];
    for (int t = 0; t < 64; t++) {
      acc += kx[t][tid];
      kn[t][tid] = acc;
    }
  }
  __syncthreads();

  // qs = softmax(q*scale, axis=-1) / knorm. wave w handles rows w*16..w*16+15.
  {
    const int w = tid >> 6, lane = tid & 63;
#pragma unroll
    for (int i = 0; i < 16; i++) {
      const int t = w * 16 + i;
      float v = qs[t][lane] * SCL;
      float m = wave_max64(v);
      float e = expf(v - m);
      float s = wave_sum64(e);
      qs[t][lane] = e / (s * kn[t][lane]);
    }
  }
  __syncthreads();

  // A[t][s] = qs[t] . kx[s] for s <= t   (stored into kn)
  {
    const int t = tid & 63, sgrp = tid >> 6;
#pragma unroll
    for (int ss = 0; ss < 16; ++ss) {
      const int s = sgrp + 4 * ss;
      if (s <= t) {
        float acc = 0.f;
        const float4* qa = (const float4*)&qs[t][0];
        const float4* ka = (const float4*)&kx[s][0];
#pragma unroll
        for (int l4 = 0; l4 < 16; l4++) {
          float4 a = qa[l4], bq = ka[l4];
          acc += a.x * bq.x + a.y * bq.y + a.z * bq.z + a.w * bq.w;
        }
        kn[t][s] = acc;
      }
    }
  }
  __syncthreads();

  // y[t][m] = sum_l qs[t][l]*Sp[l][m] + sum_{s<=t} A[t][s]*vb[s][m]
  {
    const int m = tid & 63, tg = tid >> 6;  // t = tg + 4*i
    float y[16];
#pragma unroll
    for (int i = 0; i < 16; i++) y[i] = 0.f;
    for (int l = 0; l < 64; l++) {
      const float sp = Sp[l][m];
#pragma unroll
      for (int i = 0; i < 16; i++) y[i] += qs[tg + 4 * i][l] * sp;
    }
    for (int s = 0; s < 64; s++) {
      const float vv = vb[s][m];
      const int i0 = (s - tg + 3) >> 2;   // first i with tg+4i >= s (s-tg+3 >= 0 always)
      for (int i = i0; i < 16; i++) y[i] += kn[tg + 4 * i][s] * vv;
    }
#pragma unroll
    for (int i = 0; i < 16; i++) {
      const int t = tg + 4 * i;
      Y[(size_t)(b * Tsz + c * CH + t) * Dsz + h * 64 + m] = y[i];
    }
  }
}

// ---------------------------------------------------------------------------
extern "C" void kernel_launch(void* const* d_in, const int* in_sizes, int n_in,
                              void* d_out, int out_size, void* d_ws, size_t ws_size,
                              hipStream_t stream) {
  const float* x     = (const float*)d_in[0];   // (4,2048,1024)
  const float* w     = (const float*)d_in[1];   // (3072,1024)
  const float* w_out = (const float*)d_in[2];   // (1024,1024)
  float* out = (float*)d_out;                   // (4,2048,1024)

  float* qkv  = (float*)d_ws;                          // 8192*3072
  float* KV   = qkv  + (size_t)8192 * 3072;            // 64*32*4096
  float* Ksum = KV   + (size_t)BHsz * NCH * 4096;      // 64*32*64
  float* Yb   = Ksum + (size_t)BHsz * NCH * 64;        // 8192*1024

  // 1) qkv = x @ w.T
  gemm_nt64<<<dim3(3072 / 64, 8192 / 64), 256, 0, stream>>>(x, w, qkv, 8192, 3072, 1024);
  // 2) chunked scan
  chunk_kv<<<dim3(BHsz, NCH), 64, 0, stream>>>(qkv, KV, Ksum);
  prefix_kern<<<BHsz, 256, 0, stream>>>(KV, Ksum);
  chunk_y<<<dim3(BHsz, NCH), 256, 0, stream>>>(qkv, KV, Ksum, Yb);
  // 3) out = y @ w_out
  gemm_nn64<<<dim3(1024 / 64, 8192 / 64), 256, 0, stream>>>(Yb, w_out, out, 8192, 1024, 1024);
}

// Round 2
// 789.160 us; speedup vs baseline: 2.0395x; 2.0395x over previous
//
#include <hip/hip_runtime.h>
#include <math.h>

// Problem constants (fixed by reference)
#define Bsz   4
#define Tsz   2048
#define Dsz   1024
#define Hsz   16
#define Lsz   64
#define BHsz  64          // B*H
#define CH    64          // chunk length
#define NCH   32          // T / CH
#define QKVLD 3072        // qkv row stride (3*D)
#define SCL   0.125f      // 1/sqrt(64)

typedef float  floatx4 __attribute__((ext_vector_type(4)));
typedef _Float16 half8 __attribute__((ext_vector_type(8)));
typedef _Float16 half4 __attribute__((ext_vector_type(4)));

#define AS1 __attribute__((address_space(1)))
#define AS3 __attribute__((address_space(3)))

static __device__ __forceinline__ void gload_lds16(const void* g, void* l) {
  __builtin_amdgcn_global_load_lds((const AS1 unsigned int*)g,
                                   (AS3 unsigned int*)l, 16, 0, 0);
}

static __device__ __forceinline__ float wave_max64(float v) {
#pragma unroll
  for (int off = 1; off < 64; off <<= 1) v = fmaxf(v, __shfl_xor(v, off));
  return v;
}
static __device__ __forceinline__ float wave_sum64(float v) {
#pragma unroll
  for (int off = 1; off < 64; off <<= 1) v += __shfl_xor(v, off);
  return v;
}

// ---------------------------------------------------------------------------
// fp32 -> fp16 conversion (vectorized, n % 1024 == 0)
// ---------------------------------------------------------------------------
__launch_bounds__(256)
__global__ void conv_f16(const float* __restrict__ in, _Float16* __restrict__ out) {
  const int i = (blockIdx.x * 256 + threadIdx.x) * 4;
  float4 v = *(const float4*)(in + i);
  half4 h = { (_Float16)v.x, (_Float16)v.y, (_Float16)v.z, (_Float16)v.w };
  *(half4*)(out + i) = h;
}

// ---------------------------------------------------------------------------
// w_out (1024x1024, [k][n] fp32) -> w_outT (1024x1024, [n][k] fp16)
// block (32,8), grid (32,32)
// ---------------------------------------------------------------------------
__launch_bounds__(256)
__global__ void transpose_f16(const float* __restrict__ in, _Float16* __restrict__ out) {
  __shared__ float tile[32][33];
  const int bx = blockIdx.x * 32;   // n-offset
  const int by = blockIdx.y * 32;   // k-offset
  const int tx = threadIdx.x, ty0 = threadIdx.y;
#pragma unroll
  for (int p = 0; p < 4; p++) {
    const int ty = ty0 + p * 8;
    tile[ty][tx] = in[(size_t)(by + ty) * 1024 + bx + tx];
  }
  __syncthreads();
#pragma unroll
  for (int p = 0; p < 4; p++) {
    const int ty = ty0 + p * 8;
    out[(size_t)(bx + ty) * 1024 + by + tx] = (_Float16)tile[tx][ty];
  }
}

// ---------------------------------------------------------------------------
// MFMA fp16 GEMM, B^T layout: C[m][n] = sum_k A[m][k] * B[n][k], fp32 out.
// 128x128 tile, BK=32, 256 threads (4 waves, 2x2 of 64x64),
// 16x16x32 MFMA, global_load_lds width-16 staging (m97 structure).
// M,N,K multiples of 128/128/32.
// ---------------------------------------------------------------------------
__launch_bounds__(256)
__global__ void gemm_f16_bt(const _Float16* __restrict__ A, const _Float16* __restrict__ B,
                            float* __restrict__ C, int M, int N, int K) {
  __shared__ _Float16 As[128][32];   // 8 KB
  __shared__ _Float16 Bs[128][32];   // 8 KB
  const int tid  = threadIdx.x;
  const int wave = tid >> 6, lane = tid & 63;
  const int m0 = blockIdx.y * 128, n0 = blockIdx.x * 128;
  const int wm = (wave >> 1) * 64, wn = (wave & 1) * 64;
  const int fr = lane & 15;        // fragment row (m for A / n for B / col of C)
  const int fq = lane >> 4;        // quad 0..3
  const int lr = lane >> 2;        // staging: row within 16-row group
  const int lk = (lane & 3) * 8;   // staging: k segment (8 halves = 16 B)

  floatx4 zero = {0.f, 0.f, 0.f, 0.f};
  floatx4 acc[4][4];
#pragma unroll
  for (int mt = 0; mt < 4; mt++)
#pragma unroll
    for (int nt = 0; nt < 4; nt++) acc[mt][nt] = zero;

  for (int k0 = 0; k0 < K; k0 += 32) {
    __syncthreads();   // LDS safe to overwrite
#pragma unroll
    for (int j = 0; j < 2; j++) {
      const int ia = wave * 2 + j;   // 0..7, 16 rows each
      gload_lds16(A + (size_t)(m0 + ia * 16 + lr) * K + k0 + lk, &As[ia * 16][0]);
      gload_lds16(B + (size_t)(n0 + ia * 16 + lr) * K + k0 + lk, &Bs[ia * 16][0]);
    }
    __syncthreads();   // drains vmcnt -> staged data visible

    half8 af[4], bf[4];
#pragma unroll
    for (int i = 0; i < 4; i++) {
      af[i] = *(const half8*)&As[wm + i * 16 + fr][fq * 8];
      bf[i] = *(const half8*)&Bs[wn + i * 16 + fr][fq * 8];
    }
#pragma unroll
    for (int mt = 0; mt < 4; mt++)
#pragma unroll
      for (int nt = 0; nt < 4; nt++)
        acc[mt][nt] = __builtin_amdgcn_mfma_f32_16x16x32_f16(af[mt], bf[nt], acc[mt][nt], 0, 0, 0);
  }

  // C/D layout: col = lane&15, row = quad*4 + reg  [verified m89/m91]
#pragma unroll
  for (int mt = 0; mt < 4; mt++)
#pragma unroll
    for (int nt = 0; nt < 4; nt++)
#pragma unroll
      for (int r = 0; r < 4; r++) {
        const int row = m0 + wm + mt * 16 + fq * 4 + r;
        const int col = n0 + wn + nt * 16 + fr;
        C[(size_t)row * N + col] = acc[mt][nt][r];
      }
}

// ---------------------------------------------------------------------------
// Per-chunk KV outer-product sums + per-chunk kexp sums.
// grid (BH, NCH), 64 threads. lane = column m; S[l] = state column.
// ---------------------------------------------------------------------------
__launch_bounds__(64)
__global__ void chunk_kv(const float* __restrict__ qkv, float* __restrict__ KV,
                         float* __restrict__ Ksum) {
  const int bh = blockIdx.x, c = blockIdx.y;
  const int b = bh >> 4, h = bh & 15;
  const int lane = threadIdx.x;
  __shared__ __align__(16) float kex[64];
  float S[64];
#pragma unroll
  for (int i = 0; i < 64; i++) S[i] = 0.f;
  float ksum = 0.f;
  const size_t base = ((size_t)(b * Tsz + c * CH)) * QKVLD + h * 64;
  for (int t = 0; t < CH; t++) {
    const float* row = qkv + base + (size_t)t * QKVLD;
    float ke = expf(row[1024 + lane] * SCL) + 1e-6f;  // lane as l
    float v  = row[2048 + lane];                       // lane as m
    ksum += ke;
    __syncthreads();
    kex[lane] = ke;
    __syncthreads();
    const float4* k4 = (const float4*)kex;
#pragma unroll
    for (int l4 = 0; l4 < 16; l4++) {
      float4 kk = k4[l4];
      S[l4 * 4 + 0] += kk.x * v;
      S[l4 * 4 + 1] += kk.y * v;
      S[l4 * 4 + 2] += kk.z * v;
      S[l4 * 4 + 3] += kk.w * v;
    }
  }
  float* KVp = KV + ((size_t)(bh * NCH + c)) * 4096;
#pragma unroll
  for (int l = 0; l < 64; l++) KVp[l * 64 + lane] = S[l];
  Ksum[(bh * NCH + c) * 64 + lane] = ksum;
}

// ---------------------------------------------------------------------------
// In-place exclusive prefix over chunks of KV state and Ksum. grid = BH.
// ---------------------------------------------------------------------------
__launch_bounds__(256)
__global__ void prefix_kern(float* __restrict__ KV, float* __restrict__ Ksum) {
  const int bh = blockIdx.x;
  const int tid = threadIdx.x;
#pragma unroll
  for (int i = 0; i < 16; i++) {
    const int e = tid + i * 256;
    float acc = 0.f;
    float* p = KV + (size_t)bh * NCH * 4096 + e;
    for (int c = 0; c < NCH; c++) {
      float t = p[(size_t)c * 4096];
      p[(size_t)c * 4096] = acc;
      acc += t;
    }
  }
  if (tid < 64) {
    float acc = 0.f;
    float* p = Ksum + bh * NCH * 64 + tid;
    for (int c = 0; c < NCH; c++) {
      float t = p[c * 64];
      p[c * 64] = acc;
      acc += t;
    }
  }
}

// ---------------------------------------------------------------------------
// Per-chunk output: y_t = qs_t . (Sprefix + intra-chunk causal KV).
// grid (BH, NCH), 256 threads. Writes fp16 Y for the MFMA out-GEMM.
// ---------------------------------------------------------------------------
__launch_bounds__(256)
__global__ void chunk_y(const float* __restrict__ qkv, const float* __restrict__ KV,
                        const float* __restrict__ Ksum, _Float16* __restrict__ Y) {
  const int bh = blockIdx.x, c = blockIdx.y;
  const int b = bh >> 4, h = bh & 15;
  const int tid = threadIdx.x;
  __shared__ __align__(16) float qs[64][64];  // raw q, then qs
  __shared__ __align__(16) float kx[64][64];  // kexp
  __shared__ __align__(16) float vb[64][64];  // v
  __shared__ __align__(16) float kn[64][64];  // knorm, then A (scores)
  __shared__ __align__(16) float Sp[64][64];  // state prefix

  const size_t base = ((size_t)(b * Tsz + c * CH)) * QKVLD + h * 64;
  const float* KVp = KV + ((size_t)(bh * NCH + c)) * 4096;
  {
    const int r0 = tid >> 4;            // 0..15
    const int seg4 = (tid & 15) * 4;    // 0..60
#pragma unroll
    for (int pass = 0; pass < 4; ++pass) {
      const int t = pass * 16 + r0;
      const float* row = qkv + base + (size_t)t * QKVLD;
      float4 qv = *(const float4*)(row + seg4);
      *(float4*)&qs[t][seg4] = qv;
      float4 kv = *(const float4*)(row + 1024 + seg4);
      kx[t][seg4 + 0] = expf(kv.x * SCL) + 1e-6f;
      kx[t][seg4 + 1] = expf(kv.y * SCL) + 1e-6f;
      kx[t][seg4 + 2] = expf(kv.z * SCL) + 1e-6f;
      kx[t][seg4 + 3] = expf(kv.w * SCL) + 1e-6f;
      float4 vv = *(const float4*)(row + 2048 + seg4);
      *(float4*)&vb[t][seg4] = vv;
      float4 sp = *(const float4*)(KVp + t * 64 + seg4);
      *(float4*)&Sp[t][seg4] = sp;
    }
  }
  __syncthreads();

  // knorm: exclusive chunk prefix + inclusive intra-chunk cumsum (lane = l)
  if (tid < 64) {
    float acc = Ksum[(bh * NCH + c) * 64 + tid];
    for (int t = 0; t < 64; t++) {
      acc += kx[t][tid];
      kn[t][tid] = acc;
    }
  }
  __syncthreads();

  // qs = softmax(q*scale, axis=-1) / knorm. wave w handles rows w*16..w*16+15.
  {
    const int w = tid >> 6, lane = tid & 63;
#pragma unroll
    for (int i = 0; i < 16; i++) {
      const int t = w * 16 + i;
      float v = qs[t][lane] * SCL;
      float m = wave_max64(v);
      float e = expf(v - m);
      float s = wave_sum64(e);
      qs[t][lane] = e / (s * kn[t][lane]);
    }
  }
  __syncthreads();

  // A[t][s] = qs[t] . kx[s] for s <= t   (stored into kn)
  {
    const int t = tid & 63, sgrp = tid >> 6;
#pragma unroll
    for (int ss = 0; ss < 16; ++ss) {
      const int s = sgrp + 4 * ss;
      if (s <= t) {
        float acc = 0.f;
        const float4* qa = (const float4*)&qs[t][0];
        const float4* ka = (const float4*)&kx[s][0];
#pragma unroll
        for (int l4 = 0; l4 < 16; l4++) {
          float4 a = qa[l4], bq = ka[l4];
          acc += a.x * bq.x + a.y * bq.y + a.z * bq.z + a.w * bq.w;
        }
        kn[t][s] = acc;
      }
    }
  }
  __syncthreads();

  // y[t][m] = sum_l qs[t][l]*Sp[l][m] + sum_{s<=t} A[t][s]*vb[s][m]
  {
    const int m = tid & 63, tg = tid >> 6;  // t = tg + 4*i
    float y[16];
#pragma unroll
    for (int i = 0; i < 16; i++) y[i] = 0.f;
    for (int l = 0; l < 64; l++) {
      const float sp = Sp[l][m];
#pragma unroll
      for (int i = 0; i < 16; i++) y[i] += qs[tg + 4 * i][l] * sp;
    }
    for (int s = 0; s < 64; s++) {
      const float vv = vb[s][m];
      const int i0 = (s - tg + 3) >> 2;   // first i with tg+4i >= s
      for (int i = i0; i < 16; i++) y[i] += kn[tg + 4 * i][s] * vv;
    }
#pragma unroll
    for (int i = 0; i < 16; i++) {
      const int t = tg + 4 * i;
      Y[(size_t)(b * Tsz + c * CH + t) * Dsz + h * 64 + m] = (_Float16)y[i];
    }
  }
}

// ---------------------------------------------------------------------------
extern "C" void kernel_launch(void* const* d_in, const int* in_sizes, int n_in,
                              void* d_out, int out_size, void* d_ws, size_t ws_size,
                              hipStream_t stream) {
  const float* x     = (const float*)d_in[0];   // (4,2048,1024)
  const float* w     = (const float*)d_in[1];   // (3072,1024)
  const float* w_out = (const float*)d_in[2];   // (1024,1024)
  float* out = (float*)d_out;                   // (4,2048,1024)

  // Workspace layout (fp16 elements first, then fp32). xh is dead after
  // GEMM1, so Yh aliases it (chunk_y runs strictly after GEMM1).
  _Float16* xh   = (_Float16*)d_ws;                 // 8192*1024
  _Float16* Yh   = xh;                              // alias (8192*1024)
  _Float16* wh   = xh + (size_t)8192 * 1024;        // 3072*1024
  _Float16* woT  = wh + (size_t)3072 * 1024;        // 1024*1024
  float* qkv  = (float*)(woT + (size_t)1024 * 1024);   // 8192*3072
  float* KV   = qkv  + (size_t)8192 * 3072;            // 64*32*4096
  float* Ksum = KV   + (size_t)BHsz * NCH * 4096;      // 64*32*64

  // 0) dtype prep
  conv_f16<<<8192, 256, 0, stream>>>(x, xh);            // 8M elems / 1024 per block
  conv_f16<<<3072, 256, 0, stream>>>(w, wh);
  transpose_f16<<<dim3(32, 32), dim3(32, 8), 0, stream>>>(w_out, woT);

  // 1) qkv = x @ w.T   (w already [N][K])
  gemm_f16_bt<<<dim3(3072 / 128, 8192 / 128), 256, 0, stream>>>(xh, wh, qkv, 8192, 3072, 1024);

  // 2) chunked scan
  chunk_kv<<<dim3(BHsz, NCH), 64, 0, stream>>>(qkv, KV, Ksum);
  prefix_kern<<<BHsz, 256, 0, stream>>>(KV, Ksum);
  chunk_y<<<dim3(BHsz, NCH), 256, 0, stream>>>(qkv, KV, Ksum, Yh);

  // 3) out = y @ w_out   (woT is [N][K])
  gemm_f16_bt<<<dim3(1024 / 128, 8192 / 128), 256, 0, stream>>>(Yh, woT, out, 8192, 1024, 1024);
}

// Round 3
// 308.281 us; speedup vs baseline: 5.2208x; 2.5599x over previous
//
#include <hip/hip_runtime.h>
#include <math.h>

// Problem constants (fixed by reference)
#define Bsz   4
#define Tsz   2048
#define Dsz   1024
#define Hsz   16
#define Lsz   64
#define BHsz  64          // B*H
#define CH    64          // chunk length
#define NCH   32          // T / CH
#define QKVLD 3072        // qkv row stride (3*D)
#define SCL   0.125f      // 1/sqrt(64)
#define QSC   512.0f      // qs prescale (avoid fp16 subnormals); undone in epilogue
#define QSCI  (1.0f/512.0f)

typedef float  floatx4 __attribute__((ext_vector_type(4)));
typedef _Float16 half8 __attribute__((ext_vector_type(8)));
typedef _Float16 half4 __attribute__((ext_vector_type(4)));
typedef _Float16 half2v __attribute__((ext_vector_type(2)));

#define AS1 __attribute__((address_space(1)))
#define AS3 __attribute__((address_space(3)))

static __device__ __forceinline__ void gload_lds16(const void* g, void* l) {
  __builtin_amdgcn_global_load_lds((const AS1 unsigned int*)g,
                                   (AS3 unsigned int*)l, 16, 0, 0);
}

static __device__ __forceinline__ float wave_max64(float v) {
#pragma unroll
  for (int off = 1; off < 64; off <<= 1) v = fmaxf(v, __shfl_xor(v, off));
  return v;
}
static __device__ __forceinline__ float wave_sum64(float v) {
#pragma unroll
  for (int off = 1; off < 64; off <<= 1) v += __shfl_xor(v, off);
  return v;
}

// ---------------------------------------------------------------------------
// fp32 -> fp16 conversion (vectorized, n % 1024 == 0)
// ---------------------------------------------------------------------------
__launch_bounds__(256)
__global__ void conv_f16(const float* __restrict__ in, _Float16* __restrict__ out) {
  const int i = (blockIdx.x * 256 + threadIdx.x) * 4;
  float4 v = *(const float4*)(in + i);
  half4 h = { (_Float16)v.x, (_Float16)v.y, (_Float16)v.z, (_Float16)v.w };
  *(half4*)(out + i) = h;
}

// ---------------------------------------------------------------------------
// w_out (1024x1024, [k][n] fp32) -> w_outT (1024x1024, [n][k] fp16)
// ---------------------------------------------------------------------------
__launch_bounds__(256)
__global__ void transpose_f16(const float* __restrict__ in, _Float16* __restrict__ out) {
  __shared__ float tile[32][33];
  const int bx = blockIdx.x * 32;   // n-offset
  const int by = blockIdx.y * 32;   // k-offset
  const int tx = threadIdx.x, ty0 = threadIdx.y;
#pragma unroll
  for (int p = 0; p < 4; p++) {
    const int ty = ty0 + p * 8;
    tile[ty][tx] = in[(size_t)(by + ty) * 1024 + bx + tx];
  }
  __syncthreads();
#pragma unroll
  for (int p = 0; p < 4; p++) {
    const int ty = ty0 + p * 8;
    out[(size_t)(bx + ty) * 1024 + by + tx] = (_Float16)tile[tx][ty];
  }
}

// ---------------------------------------------------------------------------
// MFMA fp16 GEMM, B^T layout, fp32 C. 128x128 tile, BK=32, m97 structure.
// ---------------------------------------------------------------------------
__launch_bounds__(256)
__global__ void gemm_f16_bt_f32(const _Float16* __restrict__ A, const _Float16* __restrict__ B,
                                float* __restrict__ C, int M, int N, int K) {
  __shared__ _Float16 As[128][32];
  __shared__ _Float16 Bs[128][32];
  const int tid  = threadIdx.x;
  const int wave = tid >> 6, lane = tid & 63;
  const int m0 = blockIdx.y * 128, n0 = blockIdx.x * 128;
  const int wm = (wave >> 1) * 64, wn = (wave & 1) * 64;
  const int fr = lane & 15;
  const int fq = lane >> 4;
  const int lr = lane >> 2;
  const int lk = (lane & 3) * 8;

  floatx4 zero = {0.f, 0.f, 0.f, 0.f};
  floatx4 acc[4][4];
#pragma unroll
  for (int mt = 0; mt < 4; mt++)
#pragma unroll
    for (int nt = 0; nt < 4; nt++) acc[mt][nt] = zero;

  for (int k0 = 0; k0 < K; k0 += 32) {
    __syncthreads();
#pragma unroll
    for (int j = 0; j < 2; j++) {
      const int ia = wave * 2 + j;
      gload_lds16(A + (size_t)(m0 + ia * 16 + lr) * K + k0 + lk, &As[ia * 16][0]);
      gload_lds16(B + (size_t)(n0 + ia * 16 + lr) * K + k0 + lk, &Bs[ia * 16][0]);
    }
    __syncthreads();

    half8 af[4], bf[4];
#pragma unroll
    for (int i = 0; i < 4; i++) {
      af[i] = *(const half8*)&As[wm + i * 16 + fr][fq * 8];
      bf[i] = *(const half8*)&Bs[wn + i * 16 + fr][fq * 8];
    }
#pragma unroll
    for (int mt = 0; mt < 4; mt++)
#pragma unroll
      for (int nt = 0; nt < 4; nt++)
        acc[mt][nt] = __builtin_amdgcn_mfma_f32_16x16x32_f16(af[mt], bf[nt], acc[mt][nt], 0, 0, 0);
  }
#pragma unroll
  for (int mt = 0; mt < 4; mt++)
#pragma unroll
    for (int nt = 0; nt < 4; nt++)
#pragma unroll
      for (int r = 0; r < 4; r++) {
        const int row = m0 + wm + mt * 16 + fq * 4 + r;
        const int col = n0 + wn + nt * 16 + fr;
        C[(size_t)row * N + col] = acc[mt][nt][r];
      }
}

// Same GEMM but fp16 C (for qkv).
__launch_bounds__(256)
__global__ void gemm_f16_bt_c16(const _Float16* __restrict__ A, const _Float16* __restrict__ B,
                                _Float16* __restrict__ C, int M, int N, int K) {
  __shared__ _Float16 As[128][32];
  __shared__ _Float16 Bs[128][32];
  const int tid  = threadIdx.x;
  const int wave = tid >> 6, lane = tid & 63;
  const int m0 = blockIdx.y * 128, n0 = blockIdx.x * 128;
  const int wm = (wave >> 1) * 64, wn = (wave & 1) * 64;
  const int fr = lane & 15;
  const int fq = lane >> 4;
  const int lr = lane >> 2;
  const int lk = (lane & 3) * 8;

  floatx4 zero = {0.f, 0.f, 0.f, 0.f};
  floatx4 acc[4][4];
#pragma unroll
  for (int mt = 0; mt < 4; mt++)
#pragma unroll
    for (int nt = 0; nt < 4; nt++) acc[mt][nt] = zero;

  for (int k0 = 0; k0 < K; k0 += 32) {
    __syncthreads();
#pragma unroll
    for (int j = 0; j < 2; j++) {
      const int ia = wave * 2 + j;
      gload_lds16(A + (size_t)(m0 + ia * 16 + lr) * K + k0 + lk, &As[ia * 16][0]);
      gload_lds16(B + (size_t)(n0 + ia * 16 + lr) * K + k0 + lk, &Bs[ia * 16][0]);
    }
    __syncthreads();

    half8 af[4], bf[4];
#pragma unroll
    for (int i = 0; i < 4; i++) {
      af[i] = *(const half8*)&As[wm + i * 16 + fr][fq * 8];
      bf[i] = *(const half8*)&Bs[wn + i * 16 + fr][fq * 8];
    }
#pragma unroll
    for (int mt = 0; mt < 4; mt++)
#pragma unroll
      for (int nt = 0; nt < 4; nt++)
        acc[mt][nt] = __builtin_amdgcn_mfma_f32_16x16x32_f16(af[mt], bf[nt], acc[mt][nt], 0, 0, 0);
  }
#pragma unroll
  for (int mt = 0; mt < 4; mt++)
#pragma unroll
    for (int nt = 0; nt < 4; nt++)
#pragma unroll
      for (int r = 0; r < 4; r++) {
        const int row = m0 + wm + mt * 16 + fq * 4 + r;
        const int col = n0 + wn + nt * 16 + fr;
        C[(size_t)row * N + col] = (_Float16)acc[mt][nt][r];
      }
}

// ---------------------------------------------------------------------------
// Per-chunk KV outer-product sums + per-chunk kexp sums (fp16 qkv input).
// grid (BH, NCH), 64 threads. lane = column m; S[l] = state column.
// KV layout: [bh][c][l][m] fp32.
// ---------------------------------------------------------------------------
__launch_bounds__(64)
__global__ void chunk_kv(const _Float16* __restrict__ qkv, float* __restrict__ KV,
                         float* __restrict__ Ksum) {
  const int bh = blockIdx.x, c = blockIdx.y;
  const int b = bh >> 4, h = bh & 15;
  const int lane = threadIdx.x;
  __shared__ __align__(16) float kex[64];
  float S[64];
#pragma unroll
  for (int i = 0; i < 64; i++) S[i] = 0.f;
  float ksum = 0.f;
  const size_t base = ((size_t)(b * Tsz + c * CH)) * QKVLD + h * 64;
  for (int t = 0; t < CH; t++) {
    const _Float16* row = qkv + base + (size_t)t * QKVLD;
    float ke = expf((float)row[1024 + lane] * SCL) + 1e-6f;
    float v  = (float)row[2048 + lane];
    ksum += ke;
    __syncthreads();
    kex[lane] = ke;
    __syncthreads();
    const float4* k4 = (const float4*)kex;
#pragma unroll
    for (int l4 = 0; l4 < 16; l4++) {
      float4 kk = k4[l4];
      S[l4 * 4 + 0] += kk.x * v;
      S[l4 * 4 + 1] += kk.y * v;
      S[l4 * 4 + 2] += kk.z * v;
      S[l4 * 4 + 3] += kk.w * v;
    }
  }
  float* KVp = KV + ((size_t)(bh * NCH + c)) * 4096;
#pragma unroll
  for (int l = 0; l < 64; l++) KVp[l * 64 + lane] = S[l];
  Ksum[(bh * NCH + c) * 64 + lane] = ksum;
}

// ---------------------------------------------------------------------------
// Exclusive prefix over chunks, element-parallel.
// Blocks 0..1023: KV (bh = blk>>4, 256 elems each). Blocks 1024..1039: Ksum.
// ---------------------------------------------------------------------------
__launch_bounds__(256)
__global__ void prefix_kern(float* __restrict__ KV, float* __restrict__ Ksum) {
  const int tid = threadIdx.x;
  if (blockIdx.x < 1024) {
    const int bh = blockIdx.x >> 4;
    const int e  = (blockIdx.x & 15) * 256 + tid;
    float* p = KV + (size_t)bh * NCH * 4096 + e;
    float acc = 0.f;
#pragma unroll 4
    for (int c = 0; c < NCH; c++) {
      float t = p[(size_t)c * 4096];
      p[(size_t)c * 4096] = acc;
      acc += t;
    }
  } else {
    const int cid = (blockIdx.x - 1024) * 256 + tid;   // 0..4095
    const int bh = cid >> 6, l = cid & 63;
    float* p = Ksum + bh * NCH * 64 + l;
    float acc = 0.f;
#pragma unroll 4
    for (int c = 0; c < NCH; c++) {
      float t = p[c * 64];
      p[c * 64] = acc;
      acc += t;
    }
  }
}

// ---------------------------------------------------------------------------
// chunk_y (MFMA version): per (bh, chunk):
//   knorm = Ksum_base + intra cumsum (wave shfl scan)
//   Qs = softmax(q*SCL)/knorm * 512          (fp16 into Ph[:,0:64])
//   A  = NT-MFMA(Qs, Kx), causal-masked      (fp16 into Ph[:,64:128])
//   Y  = NT-MFMA(Ph, Bh) / 512, Bh = [Sp^T | V^T]
// grid (BH, NCH), 256 threads (4 waves, 2x2 of 32x32).
// ---------------------------------------------------------------------------
__launch_bounds__(256)
__global__ void chunk_y(const _Float16* __restrict__ qkv, const float* __restrict__ KV,
                        const float* __restrict__ Ksum, _Float16* __restrict__ Y) {
  const int bh = blockIdx.x, c = blockIdx.y;
  const int b = bh >> 4, h = bh & 15;
  const int tid = threadIdx.x;
  const int wave = tid >> 6, lane = tid & 63;

  __shared__ float q32[64][65];                    // raw q (fp32)
  __shared__ float buf2[64][65];                   // kexp^T [l][t] -> kninv [t][l]
  __shared__ __align__(16) _Float16 kxh[64][72];   // kexp fp16 [s][l]
  __shared__ __align__(16) _Float16 Ph[64][136];   // [t][0:64]=Qs*512, [t][64:128]=A
  __shared__ __align__(16) _Float16 Bh[64][136];   // [m][0:64]=Sp^T,  [m][64:128]=V^T

  const size_t base = ((size_t)(b * Tsz + c * CH)) * QKVLD + h * 64;
  const float* KVp = KV + ((size_t)(bh * NCH + c)) * 4096;
  const int ksoff = (bh * NCH + c) * 64;

  // ---- P0: loads ----
  {
    const int rr  = tid >> 3;            // 0..31
    const int sg8 = (tid & 7) * 8;       // 0..56
#pragma unroll
    for (int p = 0; p < 2; p++) {
      const int t = p * 32 + rr;
      const _Float16* row = qkv + base + (size_t)t * QKVLD;
      half8 qv = *(const half8*)(row + sg8);
      half8 kv = *(const half8*)(row + 1024 + sg8);
      half8 kx16;
#pragma unroll
      for (int j = 0; j < 8; j++) {
        q32[t][sg8 + j] = (float)qv[j];
        float ke = expf((float)kv[j] * SCL) + 1e-6f;
        buf2[sg8 + j][t] = ke;           // transposed fp32 kexp (bank: (l+t)%32, 2-way)
        kx16[j] = (_Float16)ke;
      }
      *(half8*)&kxh[t][sg8] = kx16;
    }
  }
  {
    // V^T and Sp^T: gather 2 cols x 8 rows, write b128 rows of Bh.
    const int m2  = (tid & 31) * 2;
    const int tg8 = (tid >> 5) * 8;
    half8 vlo, vhi, slo, shi;
#pragma unroll
    for (int j = 0; j < 8; j++) {
      const int t = tg8 + j;
      half2v vv = *(const half2v*)(qkv + base + (size_t)t * QKVLD + 2048 + m2);
      vlo[j] = vv[0]; vhi[j] = vv[1];
      float2 sp = *(const float2*)(KVp + t * 64 + m2);
      slo[j] = (_Float16)sp.x; shi[j] = (_Float16)sp.y;
    }
    *(half8*)&Bh[m2][tg8]          = slo;
    *(half8*)&Bh[m2 + 1][tg8]      = shi;
    *(half8*)&Bh[m2][64 + tg8]     = vlo;
    *(half8*)&Bh[m2 + 1][64 + tg8] = vhi;
  }
  __syncthreads();

  // ---- P1: knorm scan (wave w owns l-rows w*16..w*16+15; lane = t) ----
  float kinv[16];
#pragma unroll
  for (int i = 0; i < 16; i++) {
    const int l = wave * 16 + i;
    float v = buf2[l][lane];
    #pragma unroll
    for (int off = 1; off < 64; off <<= 1) {
      float n = __shfl_up(v, off);
      if (lane >= off) v += n;
    }
    kinv[i] = QSC / (Ksum[ksoff + l] + v);
  }
  __syncthreads();          // all scan reads of buf2 done
#pragma unroll
  for (int i = 0; i < 16; i++)
    buf2[lane][wave * 16 + i] = kinv[i];   // kninv at [t][l]
  __syncthreads();

  // ---- P2: softmax + /knorm -> Ph[:,0:64] ----
#pragma unroll
  for (int i = 0; i < 16; i++) {
    const int t = wave * 16 + i;
    float v = q32[t][lane] * SCL;
    float m = wave_max64(v);
    float e = expf(v - m);
    float s = wave_sum64(e);
    Ph[t][lane] = (_Float16)((e / s) * buf2[t][lane]);
  }
  __syncthreads();

  // ---- P3: scores A = Qs . Kx^T (NT), causal mask, -> Ph[:,64:128] ----
  const int wm = (wave >> 1) * 32, wn = (wave & 1) * 32;
  const int fr = lane & 15, fq = lane >> 4;
  {
    floatx4 zero = {0.f, 0.f, 0.f, 0.f};
    floatx4 a2[2][2];
#pragma unroll
    for (int mt = 0; mt < 2; mt++)
#pragma unroll
      for (int nt = 0; nt < 2; nt++) a2[mt][nt] = zero;
#pragma unroll
    for (int ks = 0; ks < 2; ks++) {
      half8 af[2], bf[2];
#pragma unroll
      for (int i = 0; i < 2; i++) {
        af[i] = *(const half8*)&Ph[wm + i * 16 + fr][ks * 32 + fq * 8];
        bf[i] = *(const half8*)&kxh[wn + i * 16 + fr][ks * 32 + fq * 8];
      }
#pragma unroll
      for (int mt = 0; mt < 2; mt++)
#pragma unroll
        for (int nt = 0; nt < 2; nt++)
          a2[mt][nt] = __builtin_amdgcn_mfma_f32_16x16x32_f16(af[mt], bf[nt], a2[mt][nt], 0, 0, 0);
    }
    // mask s>t and write fp16 A
#pragma unroll
    for (int mt = 0; mt < 2; mt++)
#pragma unroll
      for (int nt = 0; nt < 2; nt++)
#pragma unroll
        for (int r = 0; r < 4; r++) {
          const int t = wm + mt * 16 + fq * 4 + r;
          const int s = wn + nt * 16 + fr;
          Ph[t][64 + s] = (_Float16)(s <= t ? a2[mt][nt][r] : 0.f);
        }
  }
  __syncthreads();

  // ---- P4: Y = [Qs|A] . [Sp^T|V^T]^T  (NT, K=128), scale back, store ----
  {
    floatx4 zero = {0.f, 0.f, 0.f, 0.f};
    floatx4 acc[2][2];
#pragma unroll
    for (int mt = 0; mt < 2; mt++)
#pragma unroll
      for (int nt = 0; nt < 2; nt++) acc[mt][nt] = zero;
#pragma unroll
    for (int ks = 0; ks < 4; ks++) {
      half8 af[2], bf[2];
#pragma unroll
      for (int i = 0; i < 2; i++) {
        af[i] = *(const half8*)&Ph[wm + i * 16 + fr][ks * 32 + fq * 8];
        bf[i] = *(const half8*)&Bh[wn + i * 16 + fr][ks * 32 + fq * 8];
      }
#pragma unroll
      for (int mt = 0; mt < 2; mt++)
#pragma unroll
        for (int nt = 0; nt < 2; nt++)
          acc[mt][nt] = __builtin_amdgcn_mfma_f32_16x16x32_f16(af[mt], bf[nt], acc[mt][nt], 0, 0, 0);
    }
#pragma unroll
    for (int mt = 0; mt < 2; mt++)
#pragma unroll
      for (int nt = 0; nt < 2; nt++)
#pragma unroll
        for (int r = 0; r < 4; r++) {
          const int t = wm + mt * 16 + fq * 4 + r;
          const int m = wn + nt * 16 + fr;
          Y[(size_t)(b * Tsz + c * CH + t) * Dsz + h * 64 + m] =
              (_Float16)(acc[mt][nt][r] * QSCI);
        }
  }
}

// ---------------------------------------------------------------------------
extern "C" void kernel_launch(void* const* d_in, const int* in_sizes, int n_in,
                              void* d_out, int out_size, void* d_ws, size_t ws_size,
                              hipStream_t stream) {
  const float* x     = (const float*)d_in[0];   // (4,2048,1024)
  const float* w     = (const float*)d_in[1];   // (3072,1024)
  const float* w_out = (const float*)d_in[2];   // (1024,1024)
  float* out = (float*)d_out;                   // (4,2048,1024)

  _Float16* xh   = (_Float16*)d_ws;                  // 8192*1024
  _Float16* Yh   = xh;                               // alias (xh dead after GEMM1)
  _Float16* wh   = xh + (size_t)8192 * 1024;         // 3072*1024
  _Float16* woT  = wh + (size_t)3072 * 1024;         // 1024*1024
  _Float16* qkvh = woT + (size_t)1024 * 1024;        // 8192*3072 fp16
  float* KV   = (float*)(qkvh + (size_t)8192 * 3072);   // 64*32*4096
  float* Ksum = KV + (size_t)BHsz * NCH * 4096;         // 64*32*64

  conv_f16<<<8192, 256, 0, stream>>>(x, xh);
  conv_f16<<<3072, 256, 0, stream>>>(w, wh);
  transpose_f16<<<dim3(32, 32), dim3(32, 8), 0, stream>>>(w_out, woT);

  // 1) qkv = x @ w.T (fp16 out)
  gemm_f16_bt_c16<<<dim3(24, 64), 256, 0, stream>>>(xh, wh, qkvh, 8192, 3072, 1024);

  // 2) chunked scan
  chunk_kv<<<dim3(BHsz, NCH), 64, 0, stream>>>(qkvh, KV, Ksum);
  prefix_kern<<<1040, 256, 0, stream>>>(KV, Ksum);
  chunk_y<<<dim3(BHsz, NCH), 256, 0, stream>>>(qkvh, KV, Ksum, Yh);

  // 3) out = y @ w_out
  gemm_f16_bt_f32<<<dim3(8, 64), 256, 0, stream>>>(Yh, woT, out, 8192, 1024, 1024);
}

// Round 4
// 296.845 us; speedup vs baseline: 5.4219x; 1.0385x over previous
//
#include <hip/hip_runtime.h>
#include <math.h>

// Problem constants (fixed by reference)
#define Bsz   4
#define Tsz   2048
#define Dsz   1024
#define Hsz   16
#define Lsz   64
#define BHsz  64          // B*H
#define CH    64          // chunk length
#define NCH   32          // T / CH
#define QKVLD 3072        // qkv row stride (3*D)
#define SCL   0.125f      // 1/sqrt(64)
#define QSC   512.0f      // qs prescale (avoid fp16 subnormals); undone in epilogue
#define QSCI  (1.0f/512.0f)

typedef float  floatx4 __attribute__((ext_vector_type(4)));
typedef _Float16 half8 __attribute__((ext_vector_type(8)));
typedef _Float16 half4 __attribute__((ext_vector_type(4)));
typedef _Float16 half2v __attribute__((ext_vector_type(2)));

#define AS1 __attribute__((address_space(1)))
#define AS3 __attribute__((address_space(3)))

static __device__ __forceinline__ void gload_lds16(const void* g, void* l) {
  __builtin_amdgcn_global_load_lds((const AS1 unsigned int*)g,
                                   (AS3 unsigned int*)l, 16, 0, 0);
}

static __device__ __forceinline__ float wave_max64(float v) {
#pragma unroll
  for (int off = 1; off < 64; off <<= 1) v = fmaxf(v, __shfl_xor(v, off));
  return v;
}
static __device__ __forceinline__ float wave_sum64(float v) {
#pragma unroll
  for (int off = 1; off < 64; off <<= 1) v += __shfl_xor(v, off);
  return v;
}

// ---------------------------------------------------------------------------
// Fused prep: blocks [0,8192) conv x; [8192,11264) conv w; [11264,12288) w_out^T
// ---------------------------------------------------------------------------
__launch_bounds__(256)
__global__ void prep(const float* __restrict__ x, _Float16* __restrict__ xh,
                     const float* __restrict__ w, _Float16* __restrict__ wh,
                     const float* __restrict__ wo, _Float16* __restrict__ woT) {
  const int blk = blockIdx.x, tid = threadIdx.x;
  if (blk < 11264) {
    const float* in  = (blk < 8192) ? x : w;
    _Float16*   outp = (blk < 8192) ? xh : wh;
    const int bi = (blk < 8192) ? blk : blk - 8192;
    const int i = (bi * 256 + tid) * 4;
    float4 v = *(const float4*)(in + i);
    half4 h = { (_Float16)v.x, (_Float16)v.y, (_Float16)v.z, (_Float16)v.w };
    *(half4*)(outp + i) = h;
  } else {
    __shared__ float tile[32][33];
    const int bi = blk - 11264;
    const int bx = (bi & 31) * 32;   // n-offset
    const int by = (bi >> 5) * 32;   // k-offset
    const int tx = tid & 31, ty0 = tid >> 5;
#pragma unroll
    for (int p = 0; p < 4; p++) {
      const int ty = ty0 + p * 8;
      tile[ty][tx] = wo[(size_t)(by + ty) * 1024 + bx + tx];
    }
    __syncthreads();
#pragma unroll
    for (int p = 0; p < 4; p++) {
      const int ty = ty0 + p * 8;
      woT[(size_t)(bx + ty) * 1024 + by + tx] = (_Float16)tile[tx][ty];
    }
  }
}

// ---------------------------------------------------------------------------
// MFMA fp16 GEMM, B^T layout, fp32 C. 128x128 tile, BK=32, m97 structure.
// ---------------------------------------------------------------------------
__launch_bounds__(256)
__global__ void gemm_f16_bt_f32(const _Float16* __restrict__ A, const _Float16* __restrict__ B,
                                float* __restrict__ C, int M, int N, int K) {
  __shared__ _Float16 As[128][32];
  __shared__ _Float16 Bs[128][32];
  const int tid  = threadIdx.x;
  const int wave = tid >> 6, lane = tid & 63;
  const int m0 = blockIdx.y * 128, n0 = blockIdx.x * 128;
  const int wm = (wave >> 1) * 64, wn = (wave & 1) * 64;
  const int fr = lane & 15;
  const int fq = lane >> 4;
  const int lr = lane >> 2;
  const int lk = (lane & 3) * 8;

  floatx4 zero = {0.f, 0.f, 0.f, 0.f};
  floatx4 acc[4][4];
#pragma unroll
  for (int mt = 0; mt < 4; mt++)
#pragma unroll
    for (int nt = 0; nt < 4; nt++) acc[mt][nt] = zero;

  for (int k0 = 0; k0 < K; k0 += 32) {
    __syncthreads();
#pragma unroll
    for (int j = 0; j < 2; j++) {
      const int ia = wave * 2 + j;
      gload_lds16(A + (size_t)(m0 + ia * 16 + lr) * K + k0 + lk, &As[ia * 16][0]);
      gload_lds16(B + (size_t)(n0 + ia * 16 + lr) * K + k0 + lk, &Bs[ia * 16][0]);
    }
    __syncthreads();

    half8 af[4], bf[4];
#pragma unroll
    for (int i = 0; i < 4; i++) {
      af[i] = *(const half8*)&As[wm + i * 16 + fr][fq * 8];
      bf[i] = *(const half8*)&Bs[wn + i * 16 + fr][fq * 8];
    }
#pragma unroll
    for (int mt = 0; mt < 4; mt++)
#pragma unroll
      for (int nt = 0; nt < 4; nt++)
        acc[mt][nt] = __builtin_amdgcn_mfma_f32_16x16x32_f16(af[mt], bf[nt], acc[mt][nt], 0, 0, 0);
  }
#pragma unroll
  for (int mt = 0; mt < 4; mt++)
#pragma unroll
    for (int nt = 0; nt < 4; nt++)
#pragma unroll
      for (int r = 0; r < 4; r++) {
        const int row = m0 + wm + mt * 16 + fq * 4 + r;
        const int col = n0 + wn + nt * 16 + fr;
        C[(size_t)row * N + col] = acc[mt][nt][r];
      }
}

// Same GEMM but fp16 C (for qkv).
__launch_bounds__(256)
__global__ void gemm_f16_bt_c16(const _Float16* __restrict__ A, const _Float16* __restrict__ B,
                                _Float16* __restrict__ C, int M, int N, int K) {
  __shared__ _Float16 As[128][32];
  __shared__ _Float16 Bs[128][32];
  const int tid  = threadIdx.x;
  const int wave = tid >> 6, lane = tid & 63;
  const int m0 = blockIdx.y * 128, n0 = blockIdx.x * 128;
  const int wm = (wave >> 1) * 64, wn = (wave & 1) * 64;
  const int fr = lane & 15;
  const int fq = lane >> 4;
  const int lr = lane >> 2;
  const int lk = (lane & 3) * 8;

  floatx4 zero = {0.f, 0.f, 0.f, 0.f};
  floatx4 acc[4][4];
#pragma unroll
  for (int mt = 0; mt < 4; mt++)
#pragma unroll
    for (int nt = 0; nt < 4; nt++) acc[mt][nt] = zero;

  for (int k0 = 0; k0 < K; k0 += 32) {
    __syncthreads();
#pragma unroll
    for (int j = 0; j < 2; j++) {
      const int ia = wave * 2 + j;
      gload_lds16(A + (size_t)(m0 + ia * 16 + lr) * K + k0 + lk, &As[ia * 16][0]);
      gload_lds16(B + (size_t)(n0 + ia * 16 + lr) * K + k0 + lk, &Bs[ia * 16][0]);
    }
    __syncthreads();

    half8 af[4], bf[4];
#pragma unroll
    for (int i = 0; i < 4; i++) {
      af[i] = *(const half8*)&As[wm + i * 16 + fr][fq * 8];
      bf[i] = *(const half8*)&Bs[wn + i * 16 + fr][fq * 8];
    }
#pragma unroll
    for (int mt = 0; mt < 4; mt++)
#pragma unroll
      for (int nt = 0; nt < 4; nt++)
        acc[mt][nt] = __builtin_amdgcn_mfma_f32_16x16x32_f16(af[mt], bf[nt], acc[mt][nt], 0, 0, 0);
  }
#pragma unroll
  for (int mt = 0; mt < 4; mt++)
#pragma unroll
    for (int nt = 0; nt < 4; nt++)
#pragma unroll
      for (int r = 0; r < 4; r++) {
        const int row = m0 + wm + mt * 16 + fq * 4 + r;
        const int col = n0 + wn + nt * 16 + fr;
        C[(size_t)row * N + col] = (_Float16)acc[mt][nt][r];
      }
}

// ---------------------------------------------------------------------------
// Per-chunk KV outer-product sums + per-chunk kexp sums (fp16 qkv input).
// grid (BH, NCH), 64 threads. lane = column m; S[l] = state column.
// KV layout: [bh][c][l][m] fp32.
// ---------------------------------------------------------------------------
__launch_bounds__(64)
__global__ void chunk_kv(const _Float16* __restrict__ qkv, float* __restrict__ KV,
                         float* __restrict__ Ksum) {
  const int bh = blockIdx.x, c = blockIdx.y;
  const int b = bh >> 4, h = bh & 15;
  const int lane = threadIdx.x;
  __shared__ __align__(16) float kex[64];
  float S[64];
#pragma unroll
  for (int i = 0; i < 64; i++) S[i] = 0.f;
  float ksum = 0.f;
  const size_t base = ((size_t)(b * Tsz + c * CH)) * QKVLD + h * 64;
  for (int t = 0; t < CH; t++) {
    const _Float16* row = qkv + base + (size_t)t * QKVLD;
    float ke = expf((float)row[1024 + lane] * SCL) + 1e-6f;
    float v  = (float)row[2048 + lane];
    ksum += ke;
    __syncthreads();
    kex[lane] = ke;
    __syncthreads();
    const float4* k4 = (const float4*)kex;
#pragma unroll
    for (int l4 = 0; l4 < 16; l4++) {
      float4 kk = k4[l4];
      S[l4 * 4 + 0] += kk.x * v;
      S[l4 * 4 + 1] += kk.y * v;
      S[l4 * 4 + 2] += kk.z * v;
      S[l4 * 4 + 3] += kk.w * v;
    }
  }
  float* KVp = KV + ((size_t)(bh * NCH + c)) * 4096;
#pragma unroll
  for (int l = 0; l < 64; l++) KVp[l * 64 + lane] = S[l];
  Ksum[(bh * NCH + c) * 64 + lane] = ksum;
}

// ---------------------------------------------------------------------------
// Exclusive prefix over chunks, element-parallel.
// Blocks 0..1023: KV (bh = blk>>4, 256 elems each). Blocks 1024..1039: Ksum.
// ---------------------------------------------------------------------------
__launch_bounds__(256)
__global__ void prefix_kern(float* __restrict__ KV, float* __restrict__ Ksum) {
  const int tid = threadIdx.x;
  if (blockIdx.x < 1024) {
    const int bh = blockIdx.x >> 4;
    const int e  = (blockIdx.x & 15) * 256 + tid;
    float* p = KV + (size_t)bh * NCH * 4096 + e;
    float acc = 0.f;
#pragma unroll 4
    for (int c = 0; c < NCH; c++) {
      float t = p[(size_t)c * 4096];
      p[(size_t)c * 4096] = acc;
      acc += t;
    }
  } else {
    const int cid = (blockIdx.x - 1024) * 256 + tid;   // 0..4095
    const int bh = cid >> 6, l = cid & 63;
    float* p = Ksum + bh * NCH * 64 + l;
    float acc = 0.f;
#pragma unroll 4
    for (int c = 0; c < NCH; c++) {
      float t = p[c * 64];
      p[c * 64] = acc;
      acc += t;
    }
  }
}

// ---------------------------------------------------------------------------
// chunk_y v2: 53 KB LDS (3 blocks/CU), q direct-to-reg, fp16 kexp/kninv.
//   P0: kxh[s][l] (fp16 kexp), Bh = [Sp^T | V^T]
//   P1: knorm scan over t (lane=t, column reads of kxh) -> kninv fp16 [t][l]
//   P2: Qs = softmax(q*SCL)*kninv            -> Ph[:,0:64]  (x512 prescale)
//   P3: A = NT-MFMA(Qs, Kx), causal-masked   -> Ph[:,64:128]
//   P4: Y = NT-MFMA(Ph, Bh) / 512
// grid (BH, NCH), 256 threads (4 waves, 2x2 of 32x32).
// ---------------------------------------------------------------------------
__launch_bounds__(256)
__global__ void chunk_y(const _Float16* __restrict__ qkv, const float* __restrict__ KV,
                        const float* __restrict__ Ksum, _Float16* __restrict__ Y) {
  const int bh = blockIdx.x, c = blockIdx.y;
  const int b = bh >> 4, h = bh & 15;
  const int tid = threadIdx.x;
  const int wave = tid >> 6, lane = tid & 63;

  __shared__ __align__(16) _Float16 kxh[64][72];   // kexp fp16 [s][l]   9.2 KB
  __shared__ __align__(16) _Float16 kni[64][72];   // kninv fp16 [t][l]  9.2 KB
  __shared__ __align__(16) _Float16 Ph[64][136];   // [Qs*512 | A]      17.4 KB
  __shared__ __align__(16) _Float16 Bh[64][136];   // [Sp^T | V^T]      17.4 KB

  const size_t base = ((size_t)(b * Tsz + c * CH)) * QKVLD + h * 64;
  const float* KVp = KV + ((size_t)(bh * NCH + c)) * 4096;
  const int ksoff = (bh * NCH + c) * 64;

  // q rows for this wave's softmax (P2), issued early: q[t][lane], t=wave*16+i
  _Float16 qreg[16];
#pragma unroll
  for (int i = 0; i < 16; i++)
    qreg[i] = qkv[base + (size_t)(wave * 16 + i) * QKVLD + lane];

  // ---- P0: kexp + transposed V / Sp ----
  {
    const int rr  = tid >> 3;            // 0..31
    const int sg8 = (tid & 7) * 8;       // 0..56
#pragma unroll
    for (int p = 0; p < 2; p++) {
      const int t = p * 32 + rr;
      half8 kv = *(const half8*)(qkv + base + (size_t)t * QKVLD + 1024 + sg8);
      half8 kx16;
#pragma unroll
      for (int j = 0; j < 8; j++)
        kx16[j] = (_Float16)(expf((float)kv[j] * SCL) + 1e-6f);
      *(half8*)&kxh[t][sg8] = kx16;
    }
  }
  {
    // V^T and Sp^T: gather 2 cols x 8 rows, write b128 rows of Bh.
    const int m2  = (tid & 31) * 2;
    const int tg8 = (tid >> 5) * 8;
    half8 vlo, vhi, slo, shi;
#pragma unroll
    for (int j = 0; j < 8; j++) {
      const int t = tg8 + j;
      half2v vv = *(const half2v*)(qkv + base + (size_t)t * QKVLD + 2048 + m2);
      vlo[j] = vv[0]; vhi[j] = vv[1];
      float2 sp = *(const float2*)(KVp + t * 64 + m2);
      slo[j] = (_Float16)sp.x; shi[j] = (_Float16)sp.y;
    }
    *(half8*)&Bh[m2][tg8]          = slo;
    *(half8*)&Bh[m2 + 1][tg8]      = shi;
    *(half8*)&Bh[m2][64 + tg8]     = vlo;
    *(half8*)&Bh[m2 + 1][64 + tg8] = vhi;
  }
  __syncthreads();

  // ---- P1: knorm scan (wave w owns l = w*16..w*16+15; lane = t) ----
#pragma unroll
  for (int i = 0; i < 16; i++) {
    const int l = wave * 16 + i;
    float v = (float)kxh[lane][l];        // column read (8-way, 16 insts: cheap)
#pragma unroll
    for (int off = 1; off < 64; off <<= 1) {
      float n = __shfl_up(v, off);
      if (lane >= off) v += n;
    }
    kni[lane][l] = (_Float16)(QSC / (Ksum[ksoff + l] + v));
  }
  __syncthreads();

  // ---- P2: softmax * kninv -> Ph[:,0:64] ----
#pragma unroll
  for (int i = 0; i < 16; i++) {
    const int t = wave * 16 + i;
    float v = (float)qreg[i] * SCL;
    float m = wave_max64(v);
    float e = expf(v - m);
    float s = wave_sum64(e);
    Ph[t][lane] = (_Float16)((e / s) * (float)kni[t][lane]);
  }
  __syncthreads();

  // ---- P3: scores A = Qs . Kx^T (NT), causal mask, -> Ph[:,64:128] ----
  const int wm = (wave >> 1) * 32, wn = (wave & 1) * 32;
  const int fr = lane & 15, fq = lane >> 4;
  {
    floatx4 zero = {0.f, 0.f, 0.f, 0.f};
    floatx4 a2[2][2];
#pragma unroll
    for (int mt = 0; mt < 2; mt++)
#pragma unroll
      for (int nt = 0; nt < 2; nt++) a2[mt][nt] = zero;
#pragma unroll
    for (int ks = 0; ks < 2; ks++) {
      half8 af[2], bf[2];
#pragma unroll
      for (int i = 0; i < 2; i++) {
        af[i] = *(const half8*)&Ph[wm + i * 16 + fr][ks * 32 + fq * 8];
        bf[i] = *(const half8*)&kxh[wn + i * 16 + fr][ks * 32 + fq * 8];
      }
#pragma unroll
      for (int mt = 0; mt < 2; mt++)
#pragma unroll
        for (int nt = 0; nt < 2; nt++)
          a2[mt][nt] = __builtin_amdgcn_mfma_f32_16x16x32_f16(af[mt], bf[nt], a2[mt][nt], 0, 0, 0);
    }
#pragma unroll
    for (int mt = 0; mt < 2; mt++)
#pragma unroll
      for (int nt = 0; nt < 2; nt++)
#pragma unroll
        for (int r = 0; r < 4; r++) {
          const int t = wm + mt * 16 + fq * 4 + r;
          const int s = wn + nt * 16 + fr;
          Ph[t][64 + s] = (_Float16)(s <= t ? a2[mt][nt][r] : 0.f);
        }
  }
  __syncthreads();

  // ---- P4: Y = [Qs|A] . [Sp^T|V^T]^T  (NT, K=128), scale back, store ----
  {
    floatx4 zero = {0.f, 0.f, 0.f, 0.f};
    floatx4 acc[2][2];
#pragma unroll
    for (int mt = 0; mt < 2; mt++)
#pragma unroll
      for (int nt = 0; nt < 2; nt++) acc[mt][nt] = zero;
#pragma unroll
    for (int ks = 0; ks < 4; ks++) {
      half8 af[2], bf[2];
#pragma unroll
      for (int i = 0; i < 2; i++) {
        af[i] = *(const half8*)&Ph[wm + i * 16 + fr][ks * 32 + fq * 8];
        bf[i] = *(const half8*)&Bh[wn + i * 16 + fr][ks * 32 + fq * 8];
      }
#pragma unroll
      for (int mt = 0; mt < 2; mt++)
#pragma unroll
        for (int nt = 0; nt < 2; nt++)
          acc[mt][nt] = __builtin_amdgcn_mfma_f32_16x16x32_f16(af[mt], bf[nt], acc[mt][nt], 0, 0, 0);
    }
#pragma unroll
    for (int mt = 0; mt < 2; mt++)
#pragma unroll
      for (int nt = 0; nt < 2; nt++)
#pragma unroll
        for (int r = 0; r < 4; r++) {
          const int t = wm + mt * 16 + fq * 4 + r;
          const int m = wn + nt * 16 + fr;
          Y[(size_t)(b * Tsz + c * CH + t) * Dsz + h * 64 + m] =
              (_Float16)(acc[mt][nt][r] * QSCI);
        }
  }
}

// ---------------------------------------------------------------------------
extern "C" void kernel_launch(void* const* d_in, const int* in_sizes, int n_in,
                              void* d_out, int out_size, void* d_ws, size_t ws_size,
                              hipStream_t stream) {
  const float* x     = (const float*)d_in[0];   // (4,2048,1024)
  const float* w     = (const float*)d_in[1];   // (3072,1024)
  const float* w_out = (const float*)d_in[2];   // (1024,1024)
  float* out = (float*)d_out;                   // (4,2048,1024)

  _Float16* xh   = (_Float16*)d_ws;                  // 8192*1024
  _Float16* Yh   = xh;                               // alias (xh dead after GEMM1)
  _Float16* wh   = xh + (size_t)8192 * 1024;         // 3072*1024
  _Float16* woT  = wh + (size_t)3072 * 1024;         // 1024*1024
  _Float16* qkvh = woT + (size_t)1024 * 1024;        // 8192*3072 fp16
  float* KV   = (float*)(qkvh + (size_t)8192 * 3072);   // 64*32*4096
  float* Ksum = KV + (size_t)BHsz * NCH * 4096;         // 64*32*64

  // 0) fused dtype prep
  prep<<<12288, 256, 0, stream>>>(x, xh, w, wh, w_out, woT);

  // 1) qkv = x @ w.T (fp16 out)
  gemm_f16_bt_c16<<<dim3(24, 64), 256, 0, stream>>>(xh, wh, qkvh, 8192, 3072, 1024);

  // 2) chunked scan
  chunk_kv<<<dim3(BHsz, NCH), 64, 0, stream>>>(qkvh, KV, Ksum);
  prefix_kern<<<1040, 256, 0, stream>>>(KV, Ksum);
  chunk_y<<<dim3(BHsz, NCH), 256, 0, stream>>>(qkvh, KV, Ksum, Yh);

  // 3) out = y @ w_out
  gemm_f16_bt_f32<<<dim3(8, 64), 256, 0, stream>>>(Yh, woT, out, 8192, 1024, 1024);
}

// Round 5
// 262.554 us; speedup vs baseline: 6.1300x; 1.1306x over previous
//
#include <hip/hip_runtime.h>
#include <math.h>

// Problem constants (fixed by reference)
#define Bsz   4
#define Tsz   2048
#define Dsz   1024
#define Hsz   16
#define Lsz   64
#define BHsz  64          // B*H
#define CH    64          // chunk length
#define NCH   32          // T / CH
#define QKVLD 3072        // qkv row stride (3*D)
#define SCL   0.125f      // 1/sqrt(64)
#define QSC   512.0f      // qs prescale (avoid fp16 subnormals); undone in epilogue
#define QSCI  (1.0f/512.0f)

typedef float  floatx4 __attribute__((ext_vector_type(4)));
typedef _Float16 half8 __attribute__((ext_vector_type(8)));
typedef _Float16 half4 __attribute__((ext_vector_type(4)));
typedef _Float16 half2v __attribute__((ext_vector_type(2)));

#define AS1 __attribute__((address_space(1)))
#define AS3 __attribute__((address_space(3)))

static __device__ __forceinline__ void gload_lds16(const void* g, void* l) {
  __builtin_amdgcn_global_load_lds((const AS1 unsigned int*)g,
                                   (AS3 unsigned int*)l, 16, 0, 0);
}

static __device__ __forceinline__ float wave_max64(float v) {
#pragma unroll
  for (int off = 1; off < 64; off <<= 1) v = fmaxf(v, __shfl_xor(v, off));
  return v;
}
static __device__ __forceinline__ float wave_sum64(float v) {
#pragma unroll
  for (int off = 1; off < 64; off <<= 1) v += __shfl_xor(v, off);
  return v;
}

// ---------------------------------------------------------------------------
// Fused prep: blocks [0,8192) conv x; [8192,11264) conv w; [11264,12288) w_out^T
// ---------------------------------------------------------------------------
__launch_bounds__(256)
__global__ void prep(const float* __restrict__ x, _Float16* __restrict__ xh,
                     const float* __restrict__ w, _Float16* __restrict__ wh,
                     const float* __restrict__ wo, _Float16* __restrict__ woT) {
  const int blk = blockIdx.x, tid = threadIdx.x;
  if (blk < 11264) {
    const float* in  = (blk < 8192) ? x : w;
    _Float16*   outp = (blk < 8192) ? xh : wh;
    const int bi = (blk < 8192) ? blk : blk - 8192;
    const int i = (bi * 256 + tid) * 4;
    float4 v = *(const float4*)(in + i);
    half4 h = { (_Float16)v.x, (_Float16)v.y, (_Float16)v.z, (_Float16)v.w };
    *(half4*)(outp + i) = h;
  } else {
    __shared__ float tile[32][33];
    const int bi = blk - 11264;
    const int bx = (bi & 31) * 32;   // n-offset
    const int by = (bi >> 5) * 32;   // k-offset
    const int tx = tid & 31, ty0 = tid >> 5;
#pragma unroll
    for (int p = 0; p < 4; p++) {
      const int ty = ty0 + p * 8;
      tile[ty][tx] = wo[(size_t)(by + ty) * 1024 + bx + tx];
    }
    __syncthreads();
#pragma unroll
    for (int p = 0; p < 4; p++) {
      const int ty = ty0 + p * 8;
      woT[(size_t)(bx + ty) * 1024 + by + tx] = (_Float16)tile[tx][ty];
    }
  }
}

// ---------------------------------------------------------------------------
// MFMA fp16 GEMM, B^T layout, fp32 C. 128x128 tile, BK=32, m97 structure.
// ---------------------------------------------------------------------------
__launch_bounds__(256)
__global__ void gemm_f16_bt_f32(const _Float16* __restrict__ A, const _Float16* __restrict__ B,
                                float* __restrict__ C, int M, int N, int K) {
  __shared__ _Float16 As[128][32];
  __shared__ _Float16 Bs[128][32];
  const int tid  = threadIdx.x;
  const int wave = tid >> 6, lane = tid & 63;
  const int m0 = blockIdx.y * 128, n0 = blockIdx.x * 128;
  const int wm = (wave >> 1) * 64, wn = (wave & 1) * 64;
  const int fr = lane & 15;
  const int fq = lane >> 4;
  const int lr = lane >> 2;
  const int lk = (lane & 3) * 8;

  floatx4 zero = {0.f, 0.f, 0.f, 0.f};
  floatx4 acc[4][4];
#pragma unroll
  for (int mt = 0; mt < 4; mt++)
#pragma unroll
    for (int nt = 0; nt < 4; nt++) acc[mt][nt] = zero;

  for (int k0 = 0; k0 < K; k0 += 32) {
    __syncthreads();
#pragma unroll
    for (int j = 0; j < 2; j++) {
      const int ia = wave * 2 + j;
      gload_lds16(A + (size_t)(m0 + ia * 16 + lr) * K + k0 + lk, &As[ia * 16][0]);
      gload_lds16(B + (size_t)(n0 + ia * 16 + lr) * K + k0 + lk, &Bs[ia * 16][0]);
    }
    __syncthreads();

    half8 af[4], bf[4];
#pragma unroll
    for (int i = 0; i < 4; i++) {
      af[i] = *(const half8*)&As[wm + i * 16 + fr][fq * 8];
      bf[i] = *(const half8*)&Bs[wn + i * 16 + fr][fq * 8];
    }
#pragma unroll
    for (int mt = 0; mt < 4; mt++)
#pragma unroll
      for (int nt = 0; nt < 4; nt++)
        acc[mt][nt] = __builtin_amdgcn_mfma_f32_16x16x32_f16(af[mt], bf[nt], acc[mt][nt], 0, 0, 0);
  }
#pragma unroll
  for (int mt = 0; mt < 4; mt++)
#pragma unroll
    for (int nt = 0; nt < 4; nt++)
#pragma unroll
      for (int r = 0; r < 4; r++) {
        const int row = m0 + wm + mt * 16 + fq * 4 + r;
        const int col = n0 + wn + nt * 16 + fr;
        C[(size_t)row * N + col] = acc[mt][nt][r];
      }
}

// Same GEMM but fp16 C (for qkv).
__launch_bounds__(256)
__global__ void gemm_f16_bt_c16(const _Float16* __restrict__ A, const _Float16* __restrict__ B,
                                _Float16* __restrict__ C, int M, int N, int K) {
  __shared__ _Float16 As[128][32];
  __shared__ _Float16 Bs[128][32];
  const int tid  = threadIdx.x;
  const int wave = tid >> 6, lane = tid & 63;
  const int m0 = blockIdx.y * 128, n0 = blockIdx.x * 128;
  const int wm = (wave >> 1) * 64, wn = (wave & 1) * 64;
  const int fr = lane & 15;
  const int fq = lane >> 4;
  const int lr = lane >> 2;
  const int lk = (lane & 3) * 8;

  floatx4 zero = {0.f, 0.f, 0.f, 0.f};
  floatx4 acc[4][4];
#pragma unroll
  for (int mt = 0; mt < 4; mt++)
#pragma unroll
    for (int nt = 0; nt < 4; nt++) acc[mt][nt] = zero;

  for (int k0 = 0; k0 < K; k0 += 32) {
    __syncthreads();
#pragma unroll
    for (int j = 0; j < 2; j++) {
      const int ia = wave * 2 + j;
      gload_lds16(A + (size_t)(m0 + ia * 16 + lr) * K + k0 + lk, &As[ia * 16][0]);
      gload_lds16(B + (size_t)(n0 + ia * 16 + lr) * K + k0 + lk, &Bs[ia * 16][0]);
    }
    __syncthreads();

    half8 af[4], bf[4];
#pragma unroll
    for (int i = 0; i < 4; i++) {
      af[i] = *(const half8*)&As[wm + i * 16 + fr][fq * 8];
      bf[i] = *(const half8*)&Bs[wn + i * 16 + fr][fq * 8];
    }
#pragma unroll
    for (int mt = 0; mt < 4; mt++)
#pragma unroll
      for (int nt = 0; nt < 4; nt++)
        acc[mt][nt] = __builtin_amdgcn_mfma_f32_16x16x32_f16(af[mt], bf[nt], acc[mt][nt], 0, 0, 0);
  }
#pragma unroll
  for (int mt = 0; mt < 4; mt++)
#pragma unroll
    for (int nt = 0; nt < 4; nt++)
#pragma unroll
      for (int r = 0; r < 4; r++) {
        const int row = m0 + wm + mt * 16 + fq * 4 + r;
        const int col = n0 + wn + nt * 16 + fr;
        C[(size_t)row * N + col] = (_Float16)acc[mt][nt][r];
      }
}

// ---------------------------------------------------------------------------
// chunk_kv v2 (MFMA): per chunk, S^T[m][l] = sum_t V[t][m]*Kx[t][l] via
// NT-MFMA(V^T, Kx^T). KV layout: [bh][c][m][l] fp32 (TRANSPOSED vs v1!).
// grid 512 (bh*8 + cgrp), 256 threads, 4 chunks per block.
// ---------------------------------------------------------------------------
__launch_bounds__(256)
__global__ void chunk_kv(const _Float16* __restrict__ qkv, float* __restrict__ KV,
                         float* __restrict__ Ksum) {
  const int blk = blockIdx.x;
  const int bh = blk >> 3, cgrp = blk & 7;
  const int b = bh >> 4, h = bh & 15;
  const int tid = threadIdx.x;
  const int wave = tid >> 6, lane = tid & 63;
  const int fr = lane & 15, fq = lane >> 4;
  const int m2  = (tid & 31) * 2;     // column index pair (l or m)
  const int tg8 = (tid >> 5) * 8;     // t-group of 8

  __shared__ __align__(16) _Float16 KxT[64][72];   // kexp^T [l][t]
  __shared__ __align__(16) _Float16 VT [64][72];   // V^T    [m][t]

  for (int cc = 0; cc < 4; cc++) {
    const int c = cgrp * 4 + cc;
    const size_t base = ((size_t)(b * Tsz + c * CH)) * QKVLD + h * 64;
    __syncthreads();   // LDS reuse safe
    half8 klo, khi, vlo, vhi;
#pragma unroll
    for (int j = 0; j < 8; j++) {
      const int t = tg8 + j;
      half2v kk = *(const half2v*)(qkv + base + (size_t)t * QKVLD + 1024 + m2);
      klo[j] = (_Float16)(expf((float)kk[0] * SCL) + 1e-6f);
      khi[j] = (_Float16)(expf((float)kk[1] * SCL) + 1e-6f);
      half2v vv = *(const half2v*)(qkv + base + (size_t)t * QKVLD + 2048 + m2);
      vlo[j] = vv[0]; vhi[j] = vv[1];
    }
    *(half8*)&KxT[m2][tg8]     = klo;
    *(half8*)&KxT[m2 + 1][tg8] = khi;
    *(half8*)&VT[m2][tg8]      = vlo;
    *(half8*)&VT[m2 + 1][tg8]  = vhi;
    __syncthreads();

    // wave w owns S^T rows m = w*16..w*16+15, all 4 l-tiles, K=64 (2 steps)
    floatx4 acc[4];
#pragma unroll
    for (int j = 0; j < 4; j++) acc[j] = (floatx4){0.f, 0.f, 0.f, 0.f};
#pragma unroll
    for (int ks = 0; ks < 2; ks++) {
      half8 av = *(const half8*)&VT[wave * 16 + fr][ks * 32 + fq * 8];
#pragma unroll
      for (int j = 0; j < 4; j++) {
        half8 bv = *(const half8*)&KxT[j * 16 + fr][ks * 32 + fq * 8];
        acc[j] = __builtin_amdgcn_mfma_f32_16x16x32_f16(av, bv, acc[j], 0, 0, 0);
      }
    }
    float* KVp = KV + ((size_t)(bh * NCH + c)) * 4096;
#pragma unroll
    for (int j = 0; j < 4; j++)
#pragma unroll
      for (int r = 0; r < 4; r++)
        KVp[(wave * 16 + fq * 4 + r) * 64 + j * 16 + fr] = acc[j][r];

    // ksum[l] = row-sum of KxT (threads 0..63)
    if (tid < 64) {
      float s = 0.f;
      const half8* row = (const half8*)&KxT[tid][0];
#pragma unroll
      for (int j8 = 0; j8 < 8; j8++) {
        half8 v8 = row[j8];
#pragma unroll
        for (int j = 0; j < 8; j++) s += (float)v8[j];
      }
      Ksum[(bh * NCH + c) * 64 + tid] = s;
    }
  }
}

// ---------------------------------------------------------------------------
// Exclusive prefix over chunks, element-parallel (layout-agnostic).
// Blocks 0..1023: KV (bh = blk>>4, 256 elems each). Blocks 1024..1039: Ksum.
// ---------------------------------------------------------------------------
__launch_bounds__(256)
__global__ void prefix_kern(float* __restrict__ KV, float* __restrict__ Ksum) {
  const int tid = threadIdx.x;
  if (blockIdx.x < 1024) {
    const int bh = blockIdx.x >> 4;
    const int e  = (blockIdx.x & 15) * 256 + tid;
    float* p = KV + (size_t)bh * NCH * 4096 + e;
    float acc = 0.f;
#pragma unroll 4
    for (int c = 0; c < NCH; c++) {
      float t = p[(size_t)c * 4096];
      p[(size_t)c * 4096] = acc;
      acc += t;
    }
  } else {
    const int cid = (blockIdx.x - 1024) * 256 + tid;   // 0..4095
    const int bh = cid >> 6, l = cid & 63;
    float* p = Ksum + bh * NCH * 64 + l;
    float acc = 0.f;
#pragma unroll 4
    for (int c = 0; c < NCH; c++) {
      float t = p[c * 64];
      p[c * 64] = acc;
      acc += t;
    }
  }
}

// ---------------------------------------------------------------------------
// chunk_y v3: KV now holds Sp^T[m][l] -> coalesced row loads (no gather).
//   P0: kxh[s][l] (fp16 kexp), Bh = [Sp^T | V^T]
//   P1: knorm scan over t (lane=t) -> kninv fp16 [t][l]
//   P2: Qs = softmax(q*SCL)*kninv            -> Ph[:,0:64]  (x512 prescale)
//   P3: A = NT-MFMA(Qs, Kx), causal-masked   -> Ph[:,64:128]
//   P4: Y = NT-MFMA(Ph, Bh) / 512
// grid (BH, NCH), 256 threads (4 waves, 2x2 of 32x32).
// ---------------------------------------------------------------------------
__launch_bounds__(256)
__global__ void chunk_y(const _Float16* __restrict__ qkv, const float* __restrict__ KV,
                        const float* __restrict__ Ksum, _Float16* __restrict__ Y) {
  const int bh = blockIdx.x, c = blockIdx.y;
  const int b = bh >> 4, h = bh & 15;
  const int tid = threadIdx.x;
  const int wave = tid >> 6, lane = tid & 63;

  __shared__ __align__(16) _Float16 kxh[64][72];   // kexp fp16 [s][l]
  __shared__ __align__(16) _Float16 kni[64][72];   // kninv fp16 [t][l]
  __shared__ __align__(16) _Float16 Ph[64][136];   // [Qs*512 | A]
  __shared__ __align__(16) _Float16 Bh[64][136];   // [Sp^T | V^T]

  const size_t base = ((size_t)(b * Tsz + c * CH)) * QKVLD + h * 64;
  const float* KVp = KV + ((size_t)(bh * NCH + c)) * 4096;
  const int ksoff = (bh * NCH + c) * 64;

  // q rows for this wave's softmax (P2): q[t][lane], t=wave*16+i
  _Float16 qreg[16];
#pragma unroll
  for (int i = 0; i < 16; i++)
    qreg[i] = qkv[base + (size_t)(wave * 16 + i) * QKVLD + lane];

  // ---- P0a: kexp ----
  {
    const int rr  = tid >> 3;            // 0..31
    const int sg8 = (tid & 7) * 8;       // 0..56
#pragma unroll
    for (int p = 0; p < 2; p++) {
      const int t = p * 32 + rr;
      half8 kv = *(const half8*)(qkv + base + (size_t)t * QKVLD + 1024 + sg8);
      half8 kx16;
#pragma unroll
      for (int j = 0; j < 8; j++)
        kx16[j] = (_Float16)(expf((float)kv[j] * SCL) + 1e-6f);
      *(half8*)&kxh[t][sg8] = kx16;
    }
  }
  // ---- P0b: V^T gather ----
  {
    const int m2  = (tid & 31) * 2;
    const int tg8 = (tid >> 5) * 8;
    half8 vlo, vhi;
#pragma unroll
    for (int j = 0; j < 8; j++) {
      const int t = tg8 + j;
      half2v vv = *(const half2v*)(qkv + base + (size_t)t * QKVLD + 2048 + m2);
      vlo[j] = vv[0]; vhi[j] = vv[1];
    }
    *(half8*)&Bh[m2][64 + tg8]     = vlo;
    *(half8*)&Bh[m2 + 1][64 + tg8] = vhi;
  }
  // ---- P0c: Sp^T rows (coalesced fp32 row loads) ----
  {
    const int m  = tid >> 2;             // 0..63
    const int l0 = (tid & 3) * 16;       // 0,16,32,48
#pragma unroll
    for (int q = 0; q < 2; q++) {
      float4 s0 = *(const float4*)(KVp + m * 64 + l0 + q * 8);
      float4 s1 = *(const float4*)(KVp + m * 64 + l0 + q * 8 + 4);
      half8 hh = { (_Float16)s0.x, (_Float16)s0.y, (_Float16)s0.z, (_Float16)s0.w,
                   (_Float16)s1.x, (_Float16)s1.y, (_Float16)s1.z, (_Float16)s1.w };
      *(half8*)&Bh[m][l0 + q * 8] = hh;
    }
  }
  __syncthreads();

  // ---- P1: knorm scan (wave w owns l = w*16..w*16+15; lane = t) ----
#pragma unroll
  for (int i = 0; i < 16; i++) {
    const int l = wave * 16 + i;
    float v = (float)kxh[lane][l];
#pragma unroll
    for (int off = 1; off < 64; off <<= 1) {
      float n = __shfl_up(v, off);
      if (lane >= off) v += n;
    }
    kni[lane][l] = (_Float16)(QSC / (Ksum[ksoff + l] + v));
  }
  __syncthreads();

  // ---- P2: softmax * kninv -> Ph[:,0:64] ----
#pragma unroll
  for (int i = 0; i < 16; i++) {
    const int t = wave * 16 + i;
    float v = (float)qreg[i] * SCL;
    float m = wave_max64(v);
    float e = expf(v - m);
    float s = wave_sum64(e);
    Ph[t][lane] = (_Float16)((e / s) * (float)kni[t][lane]);
  }
  __syncthreads();

  // ---- P3: scores A = Qs . Kx^T (NT), causal mask, -> Ph[:,64:128] ----
  const int wm = (wave >> 1) * 32, wn = (wave & 1) * 32;
  const int fr = lane & 15, fq = lane >> 4;
  {
    floatx4 zero = {0.f, 0.f, 0.f, 0.f};
    floatx4 a2[2][2];
#pragma unroll
    for (int mt = 0; mt < 2; mt++)
#pragma unroll
      for (int nt = 0; nt < 2; nt++) a2[mt][nt] = zero;
#pragma unroll
    for (int ks = 0; ks < 2; ks++) {
      half8 af[2], bf[2];
#pragma unroll
      for (int i = 0; i < 2; i++) {
        af[i] = *(const half8*)&Ph[wm + i * 16 + fr][ks * 32 + fq * 8];
        bf[i] = *(const half8*)&kxh[wn + i * 16 + fr][ks * 32 + fq * 8];
      }
#pragma unroll
      for (int mt = 0; mt < 2; mt++)
#pragma unroll
        for (int nt = 0; nt < 2; nt++)
          a2[mt][nt] = __builtin_amdgcn_mfma_f32_16x16x32_f16(af[mt], bf[nt], a2[mt][nt], 0, 0, 0);
    }
#pragma unroll
    for (int mt = 0; mt < 2; mt++)
#pragma unroll
      for (int nt = 0; nt < 2; nt++)
#pragma unroll
        for (int r = 0; r < 4; r++) {
          const int t = wm + mt * 16 + fq * 4 + r;
          const int s = wn + nt * 16 + fr;
          Ph[t][64 + s] = (_Float16)(s <= t ? a2[mt][nt][r] : 0.f);
        }
  }
  __syncthreads();

  // ---- P4: Y = [Qs|A] . [Sp^T|V^T]^T  (NT, K=128), scale back, store ----
  {
    floatx4 zero = {0.f, 0.f, 0.f, 0.f};
    floatx4 acc[2][2];
#pragma unroll
    for (int mt = 0; mt < 2; mt++)
#pragma unroll
      for (int nt = 0; nt < 2; nt++) acc[mt][nt] = zero;
#pragma unroll
    for (int ks = 0; ks < 4; ks++) {
      half8 af[2], bf[2];
#pragma unroll
      for (int i = 0; i < 2; i++) {
        af[i] = *(const half8*)&Ph[wm + i * 16 + fr][ks * 32 + fq * 8];
        bf[i] = *(const half8*)&Bh[wn + i * 16 + fr][ks * 32 + fq * 8];
      }
#pragma unroll
      for (int mt = 0; mt < 2; mt++)
#pragma unroll
        for (int nt = 0; nt < 2; nt++)
          acc[mt][nt] = __builtin_amdgcn_mfma_f32_16x16x32_f16(af[mt], bf[nt], acc[mt][nt], 0, 0, 0);
    }
#pragma unroll
    for (int mt = 0; mt < 2; mt++)
#pragma unroll
      for (int nt = 0; nt < 2; nt++)
#pragma unroll
        for (int r = 0; r < 4; r++) {
          const int t = wm + mt * 16 + fq * 4 + r;
          const int m = wn + nt * 16 + fr;
          Y[(size_t)(b * Tsz + c * CH + t) * Dsz + h * 64 + m] =
              (_Float16)(acc[mt][nt][r] * QSCI);
        }
  }
}

// ---------------------------------------------------------------------------
extern "C" void kernel_launch(void* const* d_in, const int* in_sizes, int n_in,
                              void* d_out, int out_size, void* d_ws, size_t ws_size,
                              hipStream_t stream) {
  const float* x     = (const float*)d_in[0];   // (4,2048,1024)
  const float* w     = (const float*)d_in[1];   // (3072,1024)
  const float* w_out = (const float*)d_in[2];   // (1024,1024)
  float* out = (float*)d_out;                   // (4,2048,1024)

  _Float16* xh   = (_Float16*)d_ws;                  // 8192*1024
  _Float16* Yh   = xh;                               // alias (xh dead after GEMM1)
  _Float16* wh   = xh + (size_t)8192 * 1024;         // 3072*1024
  _Float16* woT  = wh + (size_t)3072 * 1024;         // 1024*1024
  _Float16* qkvh = woT + (size_t)1024 * 1024;        // 8192*3072 fp16
  float* KV   = (float*)(qkvh + (size_t)8192 * 3072);   // 64*32*4096 (S^T layout)
  float* Ksum = KV + (size_t)BHsz * NCH * 4096;         // 64*32*64

  // 0) fused dtype prep
  prep<<<12288, 256, 0, stream>>>(x, xh, w, wh, w_out, woT);

  // 1) qkv = x @ w.T (fp16 out)
  gemm_f16_bt_c16<<<dim3(24, 64), 256, 0, stream>>>(xh, wh, qkvh, 8192, 3072, 1024);

  // 2) chunked scan
  chunk_kv<<<512, 256, 0, stream>>>(qkvh, KV, Ksum);
  prefix_kern<<<1040, 256, 0, stream>>>(KV, Ksum);
  chunk_y<<<dim3(BHsz, NCH), 256, 0, stream>>>(qkvh, KV, Ksum, Yh);

  // 3) out = y @ w_out
  gemm_f16_bt_f32<<<dim3(8, 64), 256, 0, stream>>>(Yh, woT, out, 8192, 1024, 1024);
}

// Round 6
// 257.785 us; speedup vs baseline: 6.2434x; 1.0185x over previous
//
#include <hip/hip_runtime.h>
#include <math.h>

// Problem constants (fixed by reference)
#define Bsz   4
#define Tsz   2048
#define Dsz   1024
#define Hsz   16
#define Lsz   64
#define BHsz  64          // B*H
#define CH    64          // chunk length
#define NCH   32          // T / CH
#define QKVLD 3072        // qkv row stride (3*D)
#define SCL   0.125f      // 1/sqrt(64)
#define QSC   512.0f      // qs prescale (avoid fp16 subnormals); undone in epilogue
#define QSCI  (1.0f/512.0f)

typedef float  floatx4 __attribute__((ext_vector_type(4)));
typedef _Float16 half8 __attribute__((ext_vector_type(8)));
typedef _Float16 half4 __attribute__((ext_vector_type(4)));
typedef _Float16 half2v __attribute__((ext_vector_type(2)));

#define AS1 __attribute__((address_space(1)))
#define AS3 __attribute__((address_space(3)))

static __device__ __forceinline__ void gload_lds16(const void* g, void* l) {
  __builtin_amdgcn_global_load_lds((const AS1 unsigned int*)g,
                                   (AS3 unsigned int*)l, 16, 0, 0);
}

static __device__ __forceinline__ float wave_max64(float v) {
#pragma unroll
  for (int off = 1; off < 64; off <<= 1) v = fmaxf(v, __shfl_xor(v, off));
  return v;
}
static __device__ __forceinline__ float wave_sum64(float v) {
#pragma unroll
  for (int off = 1; off < 64; off <<= 1) v += __shfl_xor(v, off);
  return v;
}

// ---------------------------------------------------------------------------
// Fused prep: blocks [0,8192) conv x; [8192,11264) conv w; [11264,12288) w_out^T
// ---------------------------------------------------------------------------
__launch_bounds__(256)
__global__ void prep(const float* __restrict__ x, _Float16* __restrict__ xh,
                     const float* __restrict__ w, _Float16* __restrict__ wh,
                     const float* __restrict__ wo, _Float16* __restrict__ woT) {
  const int blk = blockIdx.x, tid = threadIdx.x;
  if (blk < 11264) {
    const float* in  = (blk < 8192) ? x : w;
    _Float16*   outp = (blk < 8192) ? xh : wh;
    const int bi = (blk < 8192) ? blk : blk - 8192;
    const int i = (bi * 256 + tid) * 4;
    float4 v = *(const float4*)(in + i);
    half4 h = { (_Float16)v.x, (_Float16)v.y, (_Float16)v.z, (_Float16)v.w };
    *(half4*)(outp + i) = h;
  } else {
    __shared__ float tile[32][33];
    const int bi = blk - 11264;
    const int bx = (bi & 31) * 32;   // n-offset
    const int by = (bi >> 5) * 32;   // k-offset
    const int tx = tid & 31, ty0 = tid >> 5;
#pragma unroll
    for (int p = 0; p < 4; p++) {
      const int ty = ty0 + p * 8;
      tile[ty][tx] = wo[(size_t)(by + ty) * 1024 + bx + tx];
    }
    __syncthreads();
#pragma unroll
    for (int p = 0; p < 4; p++) {
      const int ty = ty0 + p * 8;
      woT[(size_t)(bx + ty) * 1024 + by + tx] = (_Float16)tile[tx][ty];
    }
  }
}

// ---------------------------------------------------------------------------
// MFMA fp16 GEMM, B^T layout, fp32 C. 128x128 tile, BK=32, m97 structure.
// ---------------------------------------------------------------------------
__launch_bounds__(256)
__global__ void gemm_f16_bt_f32(const _Float16* __restrict__ A, const _Float16* __restrict__ B,
                                float* __restrict__ C, int M, int N, int K) {
  __shared__ _Float16 As[128][32];
  __shared__ _Float16 Bs[128][32];
  const int tid  = threadIdx.x;
  const int wave = tid >> 6, lane = tid & 63;
  const int m0 = blockIdx.y * 128, n0 = blockIdx.x * 128;
  const int wm = (wave >> 1) * 64, wn = (wave & 1) * 64;
  const int fr = lane & 15;
  const int fq = lane >> 4;
  const int lr = lane >> 2;
  const int lk = (lane & 3) * 8;

  floatx4 zero = {0.f, 0.f, 0.f, 0.f};
  floatx4 acc[4][4];
#pragma unroll
  for (int mt = 0; mt < 4; mt++)
#pragma unroll
    for (int nt = 0; nt < 4; nt++) acc[mt][nt] = zero;

  for (int k0 = 0; k0 < K; k0 += 32) {
    __syncthreads();
#pragma unroll
    for (int j = 0; j < 2; j++) {
      const int ia = wave * 2 + j;
      gload_lds16(A + (size_t)(m0 + ia * 16 + lr) * K + k0 + lk, &As[ia * 16][0]);
      gload_lds16(B + (size_t)(n0 + ia * 16 + lr) * K + k0 + lk, &Bs[ia * 16][0]);
    }
    __syncthreads();

    half8 af[4], bf[4];
#pragma unroll
    for (int i = 0; i < 4; i++) {
      af[i] = *(const half8*)&As[wm + i * 16 + fr][fq * 8];
      bf[i] = *(const half8*)&Bs[wn + i * 16 + fr][fq * 8];
    }
#pragma unroll
    for (int mt = 0; mt < 4; mt++)
#pragma unroll
      for (int nt = 0; nt < 4; nt++)
        acc[mt][nt] = __builtin_amdgcn_mfma_f32_16x16x32_f16(af[mt], bf[nt], acc[mt][nt], 0, 0, 0);
  }
#pragma unroll
  for (int mt = 0; mt < 4; mt++)
#pragma unroll
    for (int nt = 0; nt < 4; nt++)
#pragma unroll
      for (int r = 0; r < 4; r++) {
        const int row = m0 + wm + mt * 16 + fq * 4 + r;
        const int col = n0 + wn + nt * 16 + fr;
        C[(size_t)row * N + col] = acc[mt][nt][r];
      }
}

// Same GEMM but fp16 C, with fused kexp epilogue for k-region columns
// (n in [1024,2048)): stores exp(acc*SCL)+1e-6 computed on the fp32 acc.
__launch_bounds__(256)
__global__ void gemm_f16_bt_c16(const _Float16* __restrict__ A, const _Float16* __restrict__ B,
                                _Float16* __restrict__ C, int M, int N, int K) {
  __shared__ _Float16 As[128][32];
  __shared__ _Float16 Bs[128][32];
  const int tid  = threadIdx.x;
  const int wave = tid >> 6, lane = tid & 63;
  const int m0 = blockIdx.y * 128, n0 = blockIdx.x * 128;
  const int wm = (wave >> 1) * 64, wn = (wave & 1) * 64;
  const int fr = lane & 15;
  const int fq = lane >> 4;
  const int lr = lane >> 2;
  const int lk = (lane & 3) * 8;
  const bool kreg = (n0 >= 1024) && (n0 < 2048);   // wave-uniform

  floatx4 zero = {0.f, 0.f, 0.f, 0.f};
  floatx4 acc[4][4];
#pragma unroll
  for (int mt = 0; mt < 4; mt++)
#pragma unroll
    for (int nt = 0; nt < 4; nt++) acc[mt][nt] = zero;

  for (int k0 = 0; k0 < K; k0 += 32) {
    __syncthreads();
#pragma unroll
    for (int j = 0; j < 2; j++) {
      const int ia = wave * 2 + j;
      gload_lds16(A + (size_t)(m0 + ia * 16 + lr) * K + k0 + lk, &As[ia * 16][0]);
      gload_lds16(B + (size_t)(n0 + ia * 16 + lr) * K + k0 + lk, &Bs[ia * 16][0]);
    }
    __syncthreads();

    half8 af[4], bf[4];
#pragma unroll
    for (int i = 0; i < 4; i++) {
      af[i] = *(const half8*)&As[wm + i * 16 + fr][fq * 8];
      bf[i] = *(const half8*)&Bs[wn + i * 16 + fr][fq * 8];
    }
#pragma unroll
    for (int mt = 0; mt < 4; mt++)
#pragma unroll
      for (int nt = 0; nt < 4; nt++)
        acc[mt][nt] = __builtin_amdgcn_mfma_f32_16x16x32_f16(af[mt], bf[nt], acc[mt][nt], 0, 0, 0);
  }
#pragma unroll
  for (int mt = 0; mt < 4; mt++)
#pragma unroll
    for (int nt = 0; nt < 4; nt++)
#pragma unroll
      for (int r = 0; r < 4; r++) {
        const int row = m0 + wm + mt * 16 + fq * 4 + r;
        const int col = n0 + wn + nt * 16 + fr;
        float v = acc[mt][nt][r];
        if (kreg) v = __expf(v * SCL) + 1e-6f;
        C[(size_t)row * N + col] = (_Float16)v;
      }
}

// ---------------------------------------------------------------------------
// chunk_kv (MFMA): S^T[m][l] = sum_t V[t][m]*Kx[t][l]; kexp precomputed by
// GEMM1 epilogue. KV layout: [bh][c][m][l] fp32. grid 512, 256 thr, 4 chunks.
// ---------------------------------------------------------------------------
__launch_bounds__(256)
__global__ void chunk_kv(const _Float16* __restrict__ qkv, float* __restrict__ KV,
                         float* __restrict__ Ksum) {
  const int blk = blockIdx.x;
  const int bh = blk >> 3, cgrp = blk & 7;
  const int b = bh >> 4, h = bh & 15;
  const int tid = threadIdx.x;
  const int wave = tid >> 6, lane = tid & 63;
  const int fr = lane & 15, fq = lane >> 4;
  const int m2  = (tid & 31) * 2;     // column index pair (l or m)
  const int tg8 = (tid >> 5) * 8;     // t-group of 8

  __shared__ __align__(16) _Float16 KxT[64][72];   // kexp^T [l][t]
  __shared__ __align__(16) _Float16 VT [64][72];   // V^T    [m][t]

  for (int cc = 0; cc < 4; cc++) {
    const int c = cgrp * 4 + cc;
    const size_t base = ((size_t)(b * Tsz + c * CH)) * QKVLD + h * 64;
    __syncthreads();   // LDS reuse safe
    half8 klo, khi, vlo, vhi;
#pragma unroll
    for (int j = 0; j < 8; j++) {
      const int t = tg8 + j;
      half2v kk = *(const half2v*)(qkv + base + (size_t)t * QKVLD + 1024 + m2);
      klo[j] = kk[0]; khi[j] = kk[1];
      half2v vv = *(const half2v*)(qkv + base + (size_t)t * QKVLD + 2048 + m2);
      vlo[j] = vv[0]; vhi[j] = vv[1];
    }
    *(half8*)&KxT[m2][tg8]     = klo;
    *(half8*)&KxT[m2 + 1][tg8] = khi;
    *(half8*)&VT[m2][tg8]      = vlo;
    *(half8*)&VT[m2 + 1][tg8]  = vhi;
    __syncthreads();

    // wave w owns S^T rows m = w*16..w*16+15, all 4 l-tiles, K=64 (2 steps)
    floatx4 acc[4];
#pragma unroll
    for (int j = 0; j < 4; j++) acc[j] = (floatx4){0.f, 0.f, 0.f, 0.f};
#pragma unroll
    for (int ks = 0; ks < 2; ks++) {
      half8 av = *(const half8*)&VT[wave * 16 + fr][ks * 32 + fq * 8];
#pragma unroll
      for (int j = 0; j < 4; j++) {
        half8 bv = *(const half8*)&KxT[j * 16 + fr][ks * 32 + fq * 8];
        acc[j] = __builtin_amdgcn_mfma_f32_16x16x32_f16(av, bv, acc[j], 0, 0, 0);
      }
    }
    float* KVp = KV + ((size_t)(bh * NCH + c)) * 4096;
#pragma unroll
    for (int j = 0; j < 4; j++)
#pragma unroll
      for (int r = 0; r < 4; r++)
        KVp[(wave * 16 + fq * 4 + r) * 64 + j * 16 + fr] = acc[j][r];

    // ksum[l] = row-sum of KxT (threads 0..63)
    if (tid < 64) {
      float s = 0.f;
      const half8* row = (const half8*)&KxT[tid][0];
#pragma unroll
      for (int j8 = 0; j8 < 8; j8++) {
        half8 v8 = row[j8];
#pragma unroll
        for (int j = 0; j < 8; j++) s += (float)v8[j];
      }
      Ksum[(bh * NCH + c) * 64 + tid] = s;
    }
  }
}

// ---------------------------------------------------------------------------
// Exclusive prefix over chunks, element-parallel (layout-agnostic).
// ---------------------------------------------------------------------------
__launch_bounds__(256)
__global__ void prefix_kern(float* __restrict__ KV, float* __restrict__ Ksum) {
  const int tid = threadIdx.x;
  if (blockIdx.x < 1024) {
    const int bh = blockIdx.x >> 4;
    const int e  = (blockIdx.x & 15) * 256 + tid;
    float* p = KV + (size_t)bh * NCH * 4096 + e;
    float acc = 0.f;
#pragma unroll 4
    for (int c = 0; c < NCH; c++) {
      float t = p[(size_t)c * 4096];
      p[(size_t)c * 4096] = acc;
      acc += t;
    }
  } else {
    const int cid = (blockIdx.x - 1024) * 256 + tid;   // 0..4095
    const int bh = cid >> 6, l = cid & 63;
    float* p = Ksum + bh * NCH * 64 + l;
    float acc = 0.f;
#pragma unroll 4
    for (int c = 0; c < NCH; c++) {
      float t = p[c * 64];
      p[c * 64] = acc;
      acc += t;
    }
  }
}

// ---------------------------------------------------------------------------
// chunk_y v4: kexp precomputed; knorm cumsum via triangular MFMA; staged
// coalesced epilogue. LDS 52 KB -> 3 blocks/CU.
//   P0: kxh[s][l], kxT[l][s], Bh=[Sp^T|V^T], q->regs
//   P1: kn_incl = L.Kx (tri-MFMA, A-frag from VALU); kninv -> kxT (reused)
//   P2: Qs = softmax(q*SCL)*kninv -> Ph[:,0:64]  (x512 prescale)
//   P3: A = NT-MFMA(Qs, Kx), causal-masked -> Ph[:,64:128]
//   P4: Y = NT-MFMA(Ph, Bh)/512 -> staged in kxh -> coalesced store
// grid (BH, NCH), 256 threads (4 waves).
// ---------------------------------------------------------------------------
__launch_bounds__(256)
__global__ void chunk_y(const _Float16* __restrict__ qkv, const float* __restrict__ KV,
                        const float* __restrict__ Ksum, _Float16* __restrict__ Y) {
  const int bh = blockIdx.x, c = blockIdx.y;
  const int b = bh >> 4, h = bh & 15;
  const int tid = threadIdx.x;
  const int wave = tid >> 6, lane = tid & 63;
  const int fr = lane & 15, fq = lane >> 4;

  __shared__ __align__(16) _Float16 kxh[64][72];   // kexp [s][l]; later Y tile
  __shared__ __align__(16) _Float16 kxT[64][72];   // kexp^T [l][s]; later kninv [t][l]
  __shared__ __align__(16) _Float16 Ph[64][136];   // [Qs*512 | A]
  __shared__ __align__(16) _Float16 Bh[64][136];   // [Sp^T | V^T]

  const size_t base = ((size_t)(b * Tsz + c * CH)) * QKVLD + h * 64;
  const float* KVp = KV + ((size_t)(bh * NCH + c)) * 4096;
  const int ksoff = (bh * NCH + c) * 64;

  // q rows for this wave's softmax (P2): q[t][lane], t=wave*16+i
  _Float16 qreg[16];
#pragma unroll
  for (int i = 0; i < 16; i++)
    qreg[i] = qkv[base + (size_t)(wave * 16 + i) * QKVLD + lane];

  // Ksum base per l-tile (needed in P1)
  float ksb[4];
#pragma unroll
  for (int j = 0; j < 4; j++) ksb[j] = Ksum[ksoff + j * 16 + fr];

  // ---- P0a: kexp rows (straight copy; exp done in GEMM1 epilogue) ----
  {
    const int rr  = tid >> 3;            // 0..31
    const int sg8 = (tid & 7) * 8;       // 0..56
#pragma unroll
    for (int p = 0; p < 2; p++) {
      const int t = p * 32 + rr;
      *(half8*)&kxh[t][sg8] =
          *(const half8*)(qkv + base + (size_t)t * QKVLD + 1024 + sg8);
    }
  }
  // ---- P0b: kexp^T and V^T gathers ----
  {
    const int m2  = (tid & 31) * 2;
    const int tg8 = (tid >> 5) * 8;
    half8 klo, khi, vlo, vhi;
#pragma unroll
    for (int j = 0; j < 8; j++) {
      const int t = tg8 + j;
      half2v kk = *(const half2v*)(qkv + base + (size_t)t * QKVLD + 1024 + m2);
      klo[j] = kk[0]; khi[j] = kk[1];
      half2v vv = *(const half2v*)(qkv + base + (size_t)t * QKVLD + 2048 + m2);
      vlo[j] = vv[0]; vhi[j] = vv[1];
    }
    *(half8*)&kxT[m2][tg8]         = klo;
    *(half8*)&kxT[m2 + 1][tg8]     = khi;
    *(half8*)&Bh[m2][64 + tg8]     = vlo;
    *(half8*)&Bh[m2 + 1][64 + tg8] = vhi;
  }
  // ---- P0c: Sp^T rows (coalesced fp32 row loads) ----
  {
    const int m  = tid >> 2;             // 0..63
    const int l0 = (tid & 3) * 16;       // 0,16,32,48
#pragma unroll
    for (int q = 0; q < 2; q++) {
      float4 s0 = *(const float4*)(KVp + m * 64 + l0 + q * 8);
      float4 s1 = *(const float4*)(KVp + m * 64 + l0 + q * 8 + 4);
      half8 hh = { (_Float16)s0.x, (_Float16)s0.y, (_Float16)s0.z, (_Float16)s0.w,
                   (_Float16)s1.x, (_Float16)s1.y, (_Float16)s1.z, (_Float16)s1.w };
      *(half8*)&Bh[m][l0 + q * 8] = hh;
    }
  }
  __syncthreads();

  // ---- P1: inclusive cumsum over t via tri-MFMA: kn = L . Kx ----
  // wave w owns t-strip [w*16, w*16+16); A-frag = L rows (from VALU).
  {
    floatx4 kacc[4];
#pragma unroll
    for (int j = 0; j < 4; j++) kacc[j] = (floatx4){0.f, 0.f, 0.f, 0.f};
#pragma unroll
    for (int ks = 0; ks < 2; ks++) {
      half8 af;
#pragma unroll
      for (int j = 0; j < 8; j++)
        af[j] = (ks * 32 + fq * 8 + j) <= (wave * 16 + fr) ? (_Float16)1.0f
                                                           : (_Float16)0.0f;
#pragma unroll
      for (int j = 0; j < 4; j++) {
        half8 bf = *(const half8*)&kxT[j * 16 + fr][ks * 32 + fq * 8];
        kacc[j] = __builtin_amdgcn_mfma_f32_16x16x32_f16(af, bf, kacc[j], 0, 0, 0);
      }
    }
    __syncthreads();   // all kxT reads done -> safe to overwrite with kninv
#pragma unroll
    for (int j = 0; j < 4; j++)
#pragma unroll
      for (int r = 0; r < 4; r++)
        kxT[wave * 16 + fq * 4 + r][j * 16 + fr] =
            (_Float16)(QSC / (ksb[j] + kacc[j][r]));
  }
  // no barrier: P2 reads only this wave's own kninv strip (lgkmcnt ordering)

  // ---- P2: softmax * kninv -> Ph[:,0:64] ----
#pragma unroll
  for (int i = 0; i < 16; i++) {
    const int t = wave * 16 + i;
    float v = (float)qreg[i] * SCL;
    float m = wave_max64(v);
    float e = __expf(v - m);
    float s = wave_sum64(e);
    Ph[t][lane] = (_Float16)((e / s) * (float)kxT[t][lane]);
  }
  __syncthreads();

  // ---- P3: scores A = Qs . Kx^T (NT), causal mask, -> Ph[:,64:128] ----
  const int wm = (wave >> 1) * 32, wn = (wave & 1) * 32;
  {
    floatx4 a2[2][2];
#pragma unroll
    for (int mt = 0; mt < 2; mt++)
#pragma unroll
      for (int nt = 0; nt < 2; nt++) a2[mt][nt] = (floatx4){0.f, 0.f, 0.f, 0.f};
#pragma unroll
    for (int ks = 0; ks < 2; ks++) {
      half8 af[2], bf[2];
#pragma unroll
      for (int i = 0; i < 2; i++) {
        af[i] = *(const half8*)&Ph[wm + i * 16 + fr][ks * 32 + fq * 8];
        bf[i] = *(const half8*)&kxh[wn + i * 16 + fr][ks * 32 + fq * 8];
      }
#pragma unroll
      for (int mt = 0; mt < 2; mt++)
#pragma unroll
        for (int nt = 0; nt < 2; nt++)
          a2[mt][nt] = __builtin_amdgcn_mfma_f32_16x16x32_f16(af[mt], bf[nt], a2[mt][nt], 0, 0, 0);
    }
#pragma unroll
    for (int mt = 0; mt < 2; mt++)
#pragma unroll
      for (int nt = 0; nt < 2; nt++)
#pragma unroll
        for (int r = 0; r < 4; r++) {
          const int t = wm + mt * 16 + fq * 4 + r;
          const int s = wn + nt * 16 + fr;
          Ph[t][64 + s] = (_Float16)(s <= t ? a2[mt][nt][r] : 0.f);
        }
  }
  __syncthreads();

  // ---- P4: Y = [Qs|A] . [Sp^T|V^T]^T (NT, K=128); stage into kxh ----
  {
    floatx4 acc[2][2];
#pragma unroll
    for (int mt = 0; mt < 2; mt++)
#pragma unroll
      for (int nt = 0; nt < 2; nt++) acc[mt][nt] = (floatx4){0.f, 0.f, 0.f, 0.f};
#pragma unroll
    for (int ks = 0; ks < 4; ks++) {
      half8 af[2], bf[2];
#pragma unroll
      for (int i = 0; i < 2; i++) {
        af[i] = *(const half8*)&Ph[wm + i * 16 + fr][ks * 32 + fq * 8];
        bf[i] = *(const half8*)&Bh[wn + i * 16 + fr][ks * 32 + fq * 8];
      }
#pragma unroll
      for (int mt = 0; mt < 2; mt++)
#pragma unroll
        for (int nt = 0; nt < 2; nt++)
          acc[mt][nt] = __builtin_amdgcn_mfma_f32_16x16x32_f16(af[mt], bf[nt], acc[mt][nt], 0, 0, 0);
    }
#pragma unroll
    for (int mt = 0; mt < 2; mt++)
#pragma unroll
      for (int nt = 0; nt < 2; nt++)
#pragma unroll
        for (int r = 0; r < 4; r++)
          kxh[wm + mt * 16 + fq * 4 + r][wn + nt * 16 + fr] =
              (_Float16)(acc[mt][nt][r] * QSCI);
  }
  __syncthreads();

  // coalesced store: 4 threads cover one 128 B row
  {
    const int ty = tid >> 2, sg = (tid & 3) * 16;
    _Float16* yrow = Y + (size_t)(b * Tsz + c * CH + ty) * Dsz + h * 64 + sg;
    *(half8*)(yrow)     = *(const half8*)&kxh[ty][sg];
    *(half8*)(yrow + 8) = *(const half8*)&kxh[ty][sg + 8];
  }
}

// ---------------------------------------------------------------------------
extern "C" void kernel_launch(void* const* d_in, const int* in_sizes, int n_in,
                              void* d_out, int out_size, void* d_ws, size_t ws_size,
                              hipStream_t stream) {
  const float* x     = (const float*)d_in[0];   // (4,2048,1024)
  const float* w     = (const float*)d_in[1];   // (3072,1024)
  const float* w_out = (const float*)d_in[2];   // (1024,1024)
  float* out = (float*)d_out;                   // (4,2048,1024)

  _Float16* xh   = (_Float16*)d_ws;                  // 8192*1024
  _Float16* Yh   = xh;                               // alias (xh dead after GEMM1)
  _Float16* wh   = xh + (size_t)8192 * 1024;         // 3072*1024
  _Float16* woT  = wh + (size_t)3072 * 1024;         // 1024*1024
  _Float16* qkvh = woT + (size_t)1024 * 1024;        // 8192*3072 fp16 (k-region = kexp)
  float* KV   = (float*)(qkvh + (size_t)8192 * 3072);   // 64*32*4096 (S^T layout)
  float* Ksum = KV + (size_t)BHsz * NCH * 4096;         // 64*32*64

  // 0) fused dtype prep
  prep<<<12288, 256, 0, stream>>>(x, xh, w, wh, w_out, woT);

  // 1) qkv = x @ w.T (fp16 out, kexp fused for k-columns)
  gemm_f16_bt_c16<<<dim3(24, 64), 256, 0, stream>>>(xh, wh, qkvh, 8192, 3072, 1024);

  // 2) chunked scan
  chunk_kv<<<512, 256, 0, stream>>>(qkvh, KV, Ksum);
  prefix_kern<<<1040, 256, 0, stream>>>(KV, Ksum);
  chunk_y<<<dim3(BHsz, NCH), 256, 0, stream>>>(qkvh, KV, Ksum, Yh);

  // 3) out = y @ w_out
  gemm_f16_bt_f32<<<dim3(8, 64), 256, 0, stream>>>(Yh, woT, out, 8192, 1024, 1024);
}

// Round 7
// 249.412 us; speedup vs baseline: 6.4530x; 1.0336x over previous
//
#include <hip/hip_runtime.h>
#include <math.h>

// Problem constants (fixed by reference)
#define Bsz   4
#define Tsz   2048
#define Dsz   1024
#define Hsz   16
#define Lsz   64
#define BHsz  64          // B*H
#define CH    64          // chunk length
#define NCH   32          // T / CH
#define QKVLD 3072        // qkv row stride (3*D)
#define SCL   0.125f      // 1/sqrt(64)
#define QSC   512.0f      // qs prescale (avoid fp16 subnormals); undone in epilogue
#define QSCI  (1.0f/512.0f)

typedef float  floatx4 __attribute__((ext_vector_type(4)));
typedef _Float16 half8 __attribute__((ext_vector_type(8)));
typedef _Float16 half4 __attribute__((ext_vector_type(4)));
typedef _Float16 half2v __attribute__((ext_vector_type(2)));

#define AS1 __attribute__((address_space(1)))
#define AS3 __attribute__((address_space(3)))

static __device__ __forceinline__ void gload_lds16(const void* g, void* l) {
  __builtin_amdgcn_global_load_lds((const AS1 unsigned int*)g,
                                   (AS3 unsigned int*)l, 16, 0, 0);
}

static __device__ __forceinline__ float wave_max64(float v) {
#pragma unroll
  for (int off = 1; off < 64; off <<= 1) v = fmaxf(v, __shfl_xor(v, off));
  return v;
}
static __device__ __forceinline__ float wave_sum64(float v) {
#pragma unroll
  for (int off = 1; off < 64; off <<= 1) v += __shfl_xor(v, off);
  return v;
}

// ---------------------------------------------------------------------------
// Fused prep: blocks [0,8192) conv x; [8192,11264) conv w; [11264,12288) w_out^T
// ---------------------------------------------------------------------------
__launch_bounds__(256)
__global__ void prep(const float* __restrict__ x, _Float16* __restrict__ xh,
                     const float* __restrict__ w, _Float16* __restrict__ wh,
                     const float* __restrict__ wo, _Float16* __restrict__ woT) {
  const int blk = blockIdx.x, tid = threadIdx.x;
  if (blk < 11264) {
    const float* in  = (blk < 8192) ? x : w;
    _Float16*   outp = (blk < 8192) ? xh : wh;
    const int bi = (blk < 8192) ? blk : blk - 8192;
    const int i = (bi * 256 + tid) * 4;
    float4 v = *(const float4*)(in + i);
    half4 h = { (_Float16)v.x, (_Float16)v.y, (_Float16)v.z, (_Float16)v.w };
    *(half4*)(outp + i) = h;
  } else {
    __shared__ float tile[32][33];
    const int bi = blk - 11264;
    const int bx = (bi & 31) * 32;   // n-offset
    const int by = (bi >> 5) * 32;   // k-offset
    const int tx = tid & 31, ty0 = tid >> 5;
#pragma unroll
    for (int p = 0; p < 4; p++) {
      const int ty = ty0 + p * 8;
      tile[ty][tx] = wo[(size_t)(by + ty) * 1024 + bx + tx];
    }
    __syncthreads();
#pragma unroll
    for (int p = 0; p < 4; p++) {
      const int ty = ty0 + p * 8;
      woT[(size_t)(bx + ty) * 1024 + by + tx] = (_Float16)tile[tx][ty];
    }
  }
}

// ---------------------------------------------------------------------------
// MFMA fp16 GEMM, B^T layout, fp32 C. 128x128 tile, BK=32, m97 structure.
// XCD swizzle: flat%8 -> XCD; each XCD gets an 8-m-tile band x all n-tiles
// (A band 2 MB fits per-XCD L2). Requires gridDim.y == 64.
// ---------------------------------------------------------------------------
__launch_bounds__(256)
__global__ void gemm_f16_bt_f32(const _Float16* __restrict__ A, const _Float16* __restrict__ B,
                                float* __restrict__ C, int M, int N, int K) {
  __shared__ _Float16 As[128][32];
  __shared__ _Float16 Bs[128][32];
  const int tid  = threadIdx.x;
  const int wave = tid >> 6, lane = tid & 63;
  const int flat = blockIdx.y * gridDim.x + blockIdx.x;
  const int xcd = flat & 7, g = flat >> 3;
  const int m0 = (xcd * 8 + (g & 7)) * 128;
  const int n0 = (g >> 3) * 128;
  const int wm = (wave >> 1) * 64, wn = (wave & 1) * 64;
  const int fr = lane & 15;
  const int fq = lane >> 4;
  const int lr = lane >> 2;
  const int lk = (lane & 3) * 8;

  floatx4 zero = {0.f, 0.f, 0.f, 0.f};
  floatx4 acc[4][4];
#pragma unroll
  for (int mt = 0; mt < 4; mt++)
#pragma unroll
    for (int nt = 0; nt < 4; nt++) acc[mt][nt] = zero;

  for (int k0 = 0; k0 < K; k0 += 32) {
    __syncthreads();
#pragma unroll
    for (int j = 0; j < 2; j++) {
      const int ia = wave * 2 + j;
      gload_lds16(A + (size_t)(m0 + ia * 16 + lr) * K + k0 + lk, &As[ia * 16][0]);
      gload_lds16(B + (size_t)(n0 + ia * 16 + lr) * K + k0 + lk, &Bs[ia * 16][0]);
    }
    __syncthreads();

    half8 af[4], bf[4];
#pragma unroll
    for (int i = 0; i < 4; i++) {
      af[i] = *(const half8*)&As[wm + i * 16 + fr][fq * 8];
      bf[i] = *(const half8*)&Bs[wn + i * 16 + fr][fq * 8];
    }
#pragma unroll
    for (int mt = 0; mt < 4; mt++)
#pragma unroll
      for (int nt = 0; nt < 4; nt++)
        acc[mt][nt] = __builtin_amdgcn_mfma_f32_16x16x32_f16(af[mt], bf[nt], acc[mt][nt], 0, 0, 0);
  }
#pragma unroll
  for (int mt = 0; mt < 4; mt++)
#pragma unroll
    for (int nt = 0; nt < 4; nt++)
#pragma unroll
      for (int r = 0; r < 4; r++) {
        const int row = m0 + wm + mt * 16 + fq * 4 + r;
        const int col = n0 + wn + nt * 16 + fr;
        C[(size_t)row * N + col] = acc[mt][nt][r];
      }
}

// Same GEMM but fp16 C, with fused kexp epilogue for k-region columns
// (n in [1024,2048)): stores exp(acc*SCL)+1e-6 computed on the fp32 acc.
__launch_bounds__(256)
__global__ void gemm_f16_bt_c16(const _Float16* __restrict__ A, const _Float16* __restrict__ B,
                                _Float16* __restrict__ C, int M, int N, int K) {
  __shared__ _Float16 As[128][32];
  __shared__ _Float16 Bs[128][32];
  const int tid  = threadIdx.x;
  const int wave = tid >> 6, lane = tid & 63;
  const int flat = blockIdx.y * gridDim.x + blockIdx.x;
  const int xcd = flat & 7, g = flat >> 3;
  const int m0 = (xcd * 8 + (g & 7)) * 128;
  const int n0 = (g >> 3) * 128;
  const int wm = (wave >> 1) * 64, wn = (wave & 1) * 64;
  const int fr = lane & 15;
  const int fq = lane >> 4;
  const int lr = lane >> 2;
  const int lk = (lane & 3) * 8;
  const bool kreg = (n0 >= 1024) && (n0 < 2048);   // wave-uniform

  floatx4 zero = {0.f, 0.f, 0.f, 0.f};
  floatx4 acc[4][4];
#pragma unroll
  for (int mt = 0; mt < 4; mt++)
#pragma unroll
    for (int nt = 0; nt < 4; nt++) acc[mt][nt] = zero;

  for (int k0 = 0; k0 < K; k0 += 32) {
    __syncthreads();
#pragma unroll
    for (int j = 0; j < 2; j++) {
      const int ia = wave * 2 + j;
      gload_lds16(A + (size_t)(m0 + ia * 16 + lr) * K + k0 + lk, &As[ia * 16][0]);
      gload_lds16(B + (size_t)(n0 + ia * 16 + lr) * K + k0 + lk, &Bs[ia * 16][0]);
    }
    __syncthreads();

    half8 af[4], bf[4];
#pragma unroll
    for (int i = 0; i < 4; i++) {
      af[i] = *(const half8*)&As[wm + i * 16 + fr][fq * 8];
      bf[i] = *(const half8*)&Bs[wn + i * 16 + fr][fq * 8];
    }
#pragma unroll
    for (int mt = 0; mt < 4; mt++)
#pragma unroll
      for (int nt = 0; nt < 4; nt++)
        acc[mt][nt] = __builtin_amdgcn_mfma_f32_16x16x32_f16(af[mt], bf[nt], acc[mt][nt], 0, 0, 0);
  }
#pragma unroll
  for (int mt = 0; mt < 4; mt++)
#pragma unroll
    for (int nt = 0; nt < 4; nt++)
#pragma unroll
      for (int r = 0; r < 4; r++) {
        const int row = m0 + wm + mt * 16 + fq * 4 + r;
        const int col = n0 + wn + nt * 16 + fr;
        float v = acc[mt][nt][r];
        if (kreg) v = __expf(v * SCL) + 1e-6f;
        C[(size_t)row * N + col] = (_Float16)v;
      }
}

// ---------------------------------------------------------------------------
// chunk_kv (MFMA): S^T[m][l] = sum_t V[t][m]*Kx[t][l]; kexp precomputed by
// GEMM1 epilogue. KV layout: [bh][c][m][l] fp32. grid 512, 256 thr, 4 chunks.
// ---------------------------------------------------------------------------
__launch_bounds__(256)
__global__ void chunk_kv(const _Float16* __restrict__ qkv, float* __restrict__ KV,
                         float* __restrict__ Ksum) {
  const int blk = blockIdx.x;
  const int bh = blk >> 3, cgrp = blk & 7;
  const int b = bh >> 4, h = bh & 15;
  const int tid = threadIdx.x;
  const int wave = tid >> 6, lane = tid & 63;
  const int fr = lane & 15, fq = lane >> 4;
  const int m2  = (tid & 31) * 2;     // column index pair (l or m)
  const int tg8 = (tid >> 5) * 8;     // t-group of 8

  __shared__ __align__(16) _Float16 KxT[64][72];   // kexp^T [l][t]
  __shared__ __align__(16) _Float16 VT [64][72];   // V^T    [m][t]

  for (int cc = 0; cc < 4; cc++) {
    const int c = cgrp * 4 + cc;
    const size_t base = ((size_t)(b * Tsz + c * CH)) * QKVLD + h * 64;
    __syncthreads();   // LDS reuse safe
    half8 klo, khi, vlo, vhi;
#pragma unroll
    for (int j = 0; j < 8; j++) {
      const int t = tg8 + j;
      half2v kk = *(const half2v*)(qkv + base + (size_t)t * QKVLD + 1024 + m2);
      klo[j] = kk[0]; khi[j] = kk[1];
      half2v vv = *(const half2v*)(qkv + base + (size_t)t * QKVLD + 2048 + m2);
      vlo[j] = vv[0]; vhi[j] = vv[1];
    }
    *(half8*)&KxT[m2][tg8]     = klo;
    *(half8*)&KxT[m2 + 1][tg8] = khi;
    *(half8*)&VT[m2][tg8]      = vlo;
    *(half8*)&VT[m2 + 1][tg8]  = vhi;
    __syncthreads();

    // wave w owns S^T rows m = w*16..w*16+15, all 4 l-tiles, K=64 (2 steps)
    floatx4 acc[4];
#pragma unroll
    for (int j = 0; j < 4; j++) acc[j] = (floatx4){0.f, 0.f, 0.f, 0.f};
#pragma unroll
    for (int ks = 0; ks < 2; ks++) {
      half8 av = *(const half8*)&VT[wave * 16 + fr][ks * 32 + fq * 8];
#pragma unroll
      for (int j = 0; j < 4; j++) {
        half8 bv = *(const half8*)&KxT[j * 16 + fr][ks * 32 + fq * 8];
        acc[j] = __builtin_amdgcn_mfma_f32_16x16x32_f16(av, bv, acc[j], 0, 0, 0);
      }
    }
    float* KVp = KV + ((size_t)(bh * NCH + c)) * 4096;
#pragma unroll
    for (int j = 0; j < 4; j++)
#pragma unroll
      for (int r = 0; r < 4; r++)
        KVp[(wave * 16 + fq * 4 + r) * 64 + j * 16 + fr] = acc[j][r];

    // ksum[l] = row-sum of KxT (threads 0..63)
    if (tid < 64) {
      float s = 0.f;
      const half8* row = (const half8*)&KxT[tid][0];
#pragma unroll
      for (int j8 = 0; j8 < 8; j8++) {
        half8 v8 = row[j8];
#pragma unroll
        for (int j = 0; j < 8; j++) s += (float)v8[j];
      }
      Ksum[(bh * NCH + c) * 64 + tid] = s;
    }
  }
}

// ---------------------------------------------------------------------------
// Exclusive prefix over chunks, float4-vectorized.
// Blocks 0..255: KV (bh = blk>>2, 1024 elems each). Blocks 256..259: Ksum.
// ---------------------------------------------------------------------------
__launch_bounds__(256)
__global__ void prefix_kern(float* __restrict__ KV, float* __restrict__ Ksum) {
  const int tid = threadIdx.x;
  if (blockIdx.x < 256) {
    const int bh = blockIdx.x >> 2;
    const int e  = (blockIdx.x & 3) * 1024 + tid * 4;
    float4* p = (float4*)(KV + (size_t)bh * NCH * 4096 + e);
    float4 acc = {0.f, 0.f, 0.f, 0.f};
#pragma unroll 4
    for (int c = 0; c < NCH; c++) {
      float4 t = p[(size_t)c * 1024];
      p[(size_t)c * 1024] = acc;
      acc.x += t.x; acc.y += t.y; acc.z += t.z; acc.w += t.w;
    }
  } else {
    const int cid = (blockIdx.x - 256) * 256 + tid;   // float4-chain id 0..1023
    const int bh = cid >> 4, l4 = cid & 15;
    float4* p = (float4*)(Ksum + (size_t)bh * NCH * 64) + l4;
    float4 acc = {0.f, 0.f, 0.f, 0.f};
#pragma unroll 4
    for (int c = 0; c < NCH; c++) {
      float4 t = p[c * 16];
      p[c * 16] = acc;
      acc.x += t.x; acc.y += t.y; acc.z += t.z; acc.w += t.w;
    }
  }
}

// ---------------------------------------------------------------------------
// chunk_y v5: all-coalesced global loads; transposes done in LDS.
//   P0: kxh[s][l] rows, V rows -> Ph[:,64:128], Sp^T -> Bh[:,0:64], q -> regs
//   T : LDS transpose (conflict-free b32 column reads):
//         kxh -> kxT[l][t],  Ph-v -> Bh[:,64:128] (V^T)
//   P1: kn = L.Kx (tri-MFMA); kninv -> kxT (reused)
//   P2: Qs = softmax(q*SCL)*kninv -> Ph[:,0:64]  (x512 prescale)
//   P3: A = NT-MFMA(Qs, Kx) causal-masked -> Ph[:,64:128] (v-staging dead)
//   P4: Y = NT-MFMA(Ph, Bh)/512 -> staged in kxh -> coalesced store
// grid (BH, NCH), 256 threads (4 waves).
// ---------------------------------------------------------------------------
__launch_bounds__(256)
__global__ void chunk_y(const _Float16* __restrict__ qkv, const float* __restrict__ KV,
                        const float* __restrict__ Ksum, _Float16* __restrict__ Y) {
  const int bh = blockIdx.x, c = blockIdx.y;
  const int b = bh >> 4, h = bh & 15;
  const int tid = threadIdx.x;
  const int wave = tid >> 6, lane = tid & 63;
  const int fr = lane & 15, fq = lane >> 4;

  __shared__ __align__(16) _Float16 kxh[64][72];   // kexp [s][l]; later Y tile
  __shared__ __align__(16) _Float16 kxT[64][72];   // kexp^T [l][t]; later kninv [t][l]
  __shared__ __align__(16) _Float16 Ph[64][136];   // P0: [64:128]=V rows; then [Qs|A]
  __shared__ __align__(16) _Float16 Bh[64][136];   // [Sp^T | V^T]

  const size_t base = ((size_t)(b * Tsz + c * CH)) * QKVLD + h * 64;
  const float* KVp = KV + ((size_t)(bh * NCH + c)) * 4096;
  const int ksoff = (bh * NCH + c) * 64;

  // q rows for this wave's softmax (P2): q[t][lane], t=wave*16+i
  _Float16 qreg[16];
#pragma unroll
  for (int i = 0; i < 16; i++)
    qreg[i] = qkv[base + (size_t)(wave * 16 + i) * QKVLD + lane];

  // Ksum base per l-tile (needed in P1)
  float ksb[4];
#pragma unroll
  for (int j = 0; j < 4; j++) ksb[j] = Ksum[ksoff + j * 16 + fr];

  // ---- P0: coalesced row loads ----
  {
    const int rr  = tid >> 3;            // 0..31
    const int sg8 = (tid & 7) * 8;       // 0..56
#pragma unroll
    for (int p = 0; p < 2; p++) {
      const int t = p * 32 + rr;
      *(half8*)&kxh[t][sg8] =
          *(const half8*)(qkv + base + (size_t)t * QKVLD + 1024 + sg8);
      *(half8*)&Ph[t][64 + sg8] =
          *(const half8*)(qkv + base + (size_t)t * QKVLD + 2048 + sg8);
    }
  }
  // Sp^T rows (coalesced fp32 row loads)
  {
    const int m  = tid >> 2;             // 0..63
    const int l0 = (tid & 3) * 16;       // 0,16,32,48
#pragma unroll
    for (int q = 0; q < 2; q++) {
      float4 s0 = *(const float4*)(KVp + m * 64 + l0 + q * 8);
      float4 s1 = *(const float4*)(KVp + m * 64 + l0 + q * 8 + 4);
      half8 hh = { (_Float16)s0.x, (_Float16)s0.y, (_Float16)s0.z, (_Float16)s0.w,
                   (_Float16)s1.x, (_Float16)s1.y, (_Float16)s1.z, (_Float16)s1.w };
      *(half8*)&Bh[m][l0 + q * 8] = hh;
    }
  }
  __syncthreads();

  // ---- T: LDS transposes (b32 column reads, lane=col -> conflict-free) ----
  {
    const int l2  = (tid & 31) * 2;      // even column pair
    const int tg8 = (tid >> 5) * 8;      // 8-row group
    half8 k0, k1, v0, v1;
#pragma unroll
    for (int j = 0; j < 8; j++) {
      const int t = tg8 + j;
      half2v kk = *(const half2v*)&kxh[t][l2];
      k0[j] = kk[0]; k1[j] = kk[1];
      half2v vv = *(const half2v*)&Ph[t][64 + l2];
      v0[j] = vv[0]; v1[j] = vv[1];
    }
    *(half8*)&kxT[l2][tg8]          = k0;
    *(half8*)&kxT[l2 + 1][tg8]      = k1;
    *(half8*)&Bh[l2][64 + tg8]      = v0;
    *(half8*)&Bh[l2 + 1][64 + tg8]  = v1;
  }
  __syncthreads();

  // ---- P1: inclusive cumsum over t via tri-MFMA: kn = L . Kx ----
  {
    floatx4 kacc[4];
#pragma unroll
    for (int j = 0; j < 4; j++) kacc[j] = (floatx4){0.f, 0.f, 0.f, 0.f};
#pragma unroll
    for (int ks = 0; ks < 2; ks++) {
      half8 af;
#pragma unroll
      for (int j = 0; j < 8; j++)
        af[j] = (ks * 32 + fq * 8 + j) <= (wave * 16 + fr) ? (_Float16)1.0f
                                                           : (_Float16)0.0f;
#pragma unroll
      for (int j = 0; j < 4; j++) {
        half8 bf = *(const half8*)&kxT[j * 16 + fr][ks * 32 + fq * 8];
        kacc[j] = __builtin_amdgcn_mfma_f32_16x16x32_f16(af, bf, kacc[j], 0, 0, 0);
      }
    }
    __syncthreads();   // all kxT reads done -> safe to overwrite with kninv
#pragma unroll
    for (int j = 0; j < 4; j++)
#pragma unroll
      for (int r = 0; r < 4; r++)
        kxT[wave * 16 + fq * 4 + r][j * 16 + fr] =
            (_Float16)(QSC / (ksb[j] + kacc[j][r]));
  }
  // no barrier: P2 reads only this wave's own kninv strip

  // ---- P2: softmax * kninv -> Ph[:,0:64] ----
#pragma unroll
  for (int i = 0; i < 16; i++) {
    const int t = wave * 16 + i;
    float v = (float)qreg[i] * SCL;
    float m = wave_max64(v);
    float e = __expf(v - m);
    float s = wave_sum64(e);
    Ph[t][lane] = (_Float16)((e / s) * (float)kxT[t][lane]);
  }
  __syncthreads();

  // ---- P3: scores A = Qs . Kx^T (NT), causal mask, -> Ph[:,64:128] ----
  const int wm = (wave >> 1) * 32, wn = (wave & 1) * 32;
  {
    floatx4 a2[2][2];
#pragma unroll
    for (int mt = 0; mt < 2; mt++)
#pragma unroll
      for (int nt = 0; nt < 2; nt++) a2[mt][nt] = (floatx4){0.f, 0.f, 0.f, 0.f};
#pragma unroll
    for (int ks = 0; ks < 2; ks++) {
      half8 af[2], bf[2];
#pragma unroll
      for (int i = 0; i < 2; i++) {
        af[i] = *(const half8*)&Ph[wm + i * 16 + fr][ks * 32 + fq * 8];
        bf[i] = *(const half8*)&kxh[wn + i * 16 + fr][ks * 32 + fq * 8];
      }
#pragma unroll
      for (int mt = 0; mt < 2; mt++)
#pragma unroll
        for (int nt = 0; nt < 2; nt++)
          a2[mt][nt] = __builtin_amdgcn_mfma_f32_16x16x32_f16(af[mt], bf[nt], a2[mt][nt], 0, 0, 0);
    }
#pragma unroll
    for (int mt = 0; mt < 2; mt++)
#pragma unroll
      for (int nt = 0; nt < 2; nt++)
#pragma unroll
        for (int r = 0; r < 4; r++) {
          const int t = wm + mt * 16 + fq * 4 + r;
          const int s = wn + nt * 16 + fr;
          Ph[t][64 + s] = (_Float16)(s <= t ? a2[mt][nt][r] : 0.f);
        }
  }
  __syncthreads();

  // ---- P4: Y = [Qs|A] . [Sp^T|V^T]^T (NT, K=128); stage into kxh ----
  {
    floatx4 acc[2][2];
#pragma unroll
    for (int mt = 0; mt < 2; mt++)
#pragma unroll
      for (int nt = 0; nt < 2; nt++) acc[mt][nt] = (floatx4){0.f, 0.f, 0.f, 0.f};
#pragma unroll
    for (int ks = 0; ks < 4; ks++) {
      half8 af[2], bf[2];
#pragma unroll
      for (int i = 0; i < 2; i++) {
        af[i] = *(const half8*)&Ph[wm + i * 16 + fr][ks * 32 + fq * 8];
        bf[i] = *(const half8*)&Bh[wn + i * 16 + fr][ks * 32 + fq * 8];
      }
#pragma unroll
      for (int mt = 0; mt < 2; mt++)
#pragma unroll
        for (int nt = 0; nt < 2; nt++)
          acc[mt][nt] = __builtin_amdgcn_mfma_f32_16x16x32_f16(af[mt], bf[nt], acc[mt][nt], 0, 0, 0);
    }
#pragma unroll
    for (int mt = 0; mt < 2; mt++)
#pragma unroll
      for (int nt = 0; nt < 2; nt++)
#pragma unroll
        for (int r = 0; r < 4; r++)
          kxh[wm + mt * 16 + fq * 4 + r][wn + nt * 16 + fr] =
              (_Float16)(acc[mt][nt][r] * QSCI);
  }
  __syncthreads();

  // coalesced store: 4 threads cover one 128 B row
  {
    const int ty = tid >> 2, sg = (tid & 3) * 16;
    _Float16* yrow = Y + (size_t)(b * Tsz + c * CH + ty) * Dsz + h * 64 + sg;
    *(half8*)(yrow)     = *(const half8*)&kxh[ty][sg];
    *(half8*)(yrow + 8) = *(const half8*)&kxh[ty][sg + 8];
  }
}

// ---------------------------------------------------------------------------
extern "C" void kernel_launch(void* const* d_in, const int* in_sizes, int n_in,
                              void* d_out, int out_size, void* d_ws, size_t ws_size,
                              hipStream_t stream) {
  const float* x     = (const float*)d_in[0];   // (4,2048,1024)
  const float* w     = (const float*)d_in[1];   // (3072,1024)
  const float* w_out = (const float*)d_in[2];   // (1024,1024)
  float* out = (float*)d_out;                   // (4,2048,1024)

  _Float16* xh   = (_Float16*)d_ws;                  // 8192*1024
  _Float16* Yh   = xh;                               // alias (xh dead after GEMM1)
  _Float16* wh   = xh + (size_t)8192 * 1024;         // 3072*1024
  _Float16* woT  = wh + (size_t)3072 * 1024;         // 1024*1024
  _Float16* qkvh = woT + (size_t)1024 * 1024;        // 8192*3072 fp16 (k-region = kexp)
  float* KV   = (float*)(qkvh + (size_t)8192 * 3072);   // 64*32*4096 (S^T layout)
  float* Ksum = KV + (size_t)BHsz * NCH * 4096;         // 64*32*64

  // 0) fused dtype prep
  prep<<<12288, 256, 0, stream>>>(x, xh, w, wh, w_out, woT);

  // 1) qkv = x @ w.T (fp16 out, kexp fused for k-columns)
  gemm_f16_bt_c16<<<dim3(24, 64), 256, 0, stream>>>(xh, wh, qkvh, 8192, 3072, 1024);

  // 2) chunked scan
  chunk_kv<<<512, 256, 0, stream>>>(qkvh, KV, Ksum);
  prefix_kern<<<260, 256, 0, stream>>>(KV, Ksum);
  chunk_y<<<dim3(BHsz, NCH), 256, 0, stream>>>(qkvh, KV, Ksum, Yh);

  // 3) out = y @ w_out
  gemm_f16_bt_f32<<<dim3(8, 64), 256, 0, stream>>>(Yh, woT, out, 8192, 1024, 1024);
}